// Round 2
// baseline (523.181 us; speedup 1.0000x reference)
//
#include <hip/hip_runtime.h>
#include <math.h>

#define BB 512   // batch
#define LL 512   // seq len
#define DD 100   // emb dim
#define HH 3     // hidden
#define VV 23757 // wd vocab
#define PP 57    // pos vocab

__device__ __forceinline__ float rcp_(float x) { return __builtin_amdgcn_rcpf(x); }
__device__ __forceinline__ float sigm(float x) { return rcp_(1.f + __expf(-x)); }
__device__ __forceinline__ float tanh_(float x) { return 1.f - 2.f * rcp_(__expf(2.f * x) + 1.f); }

// ---------------------------------------------------------------------------
// 1. Small tables: E (conv folded into wd wih0), beff (biases), Gp (pos table)
//    E layout: [dg(18)][tap(4)][d(100)]; tap t reads source position l-2+t.
// ---------------------------------------------------------------------------
__global__ void k_build_tables(const float* __restrict__ wd_wih0, const float* __restrict__ wd_bih0,
                               const float* __restrict__ cw2, const float* __restrict__ cb2,
                               const float* __restrict__ cw3, const float* __restrict__ cb3,
                               const float* __restrict__ cw4, const float* __restrict__ cb4,
                               const float* __restrict__ pos_emb,
                               const float* __restrict__ pos_wih0, const float* __restrict__ pos_bih0,
                               float* __restrict__ E, float* __restrict__ beff, float* __restrict__ Gp)
{
    int idx = blockIdx.x * blockDim.x + threadIdx.x;
    if (idx < 7200) {
        int d  = idx % 100;
        int tt = (idx / 100) % 4;
        int dg = idx / 400;
        const float* wih = wd_wih0 + dg * 144;
        float acc = 0.f;
        // c2: y[l] = w2[0]x[l-1]+w2[1]x[l]        (K=2,pad=1)
        // c3: y[l] = w3[0]x[l-1]+w3[1]x[l]+w3[2]x[l+1]
        // c4: y[l] = w4[0]x[l-2]+w4[1]x[l-1]+w4[2]x[l]+w4[3]x[l+1]
        if (tt == 0) {        // offset -2
            for (int o = 0; o < 48; ++o) acc += wih[96 + o] * cw4[o * 400 + d * 4 + 0];
        } else if (tt == 1) { // offset -1
            for (int o = 0; o < 48; ++o) acc += wih[o]      * cw2[o * 200 + d * 2 + 0];
            for (int o = 0; o < 48; ++o) acc += wih[48 + o] * cw3[o * 300 + d * 3 + 0];
            for (int o = 0; o < 48; ++o) acc += wih[96 + o] * cw4[o * 400 + d * 4 + 1];
        } else if (tt == 2) { // offset 0
            for (int o = 0; o < 48; ++o) acc += wih[o]      * cw2[o * 200 + d * 2 + 1];
            for (int o = 0; o < 48; ++o) acc += wih[48 + o] * cw3[o * 300 + d * 3 + 1];
            for (int o = 0; o < 48; ++o) acc += wih[96 + o] * cw4[o * 400 + d * 4 + 2];
        } else {              // offset +1
            for (int o = 0; o < 48; ++o) acc += wih[48 + o] * cw3[o * 300 + d * 3 + 2];
            for (int o = 0; o < 48; ++o) acc += wih[96 + o] * cw4[o * 400 + d * 4 + 3];
        }
        E[idx] = acc;
    } else if (idx < 7218) {
        int dg = idx - 7200;
        float acc = wd_bih0[dg];
        for (int o = 0; o < 48; ++o) acc += wd_wih0[dg * 144 + o]      * cb2[o];
        for (int o = 0; o < 48; ++o) acc += wd_wih0[dg * 144 + 48 + o] * cb3[o];
        for (int o = 0; o < 48; ++o) acc += wd_wih0[dg * 144 + 96 + o] * cb4[o];
        beff[dg] = acc;
    } else if (idx < 7218 + PP * 18) {
        int k = idx - 7218;
        int dg = k % 18;
        int p  = k / 18;
        float acc = pos_bih0[dg];
        for (int d = 0; d < 100; ++d) acc += pos_emb[p * 100 + d] * pos_wih0[dg * 100 + d];
        Gp[p * 18 + dg] = acc;
    }
}

// ---------------------------------------------------------------------------
// 2. P[v][tap][dg] = wd_emb[v,:] . E[dg][tap][:]
// ---------------------------------------------------------------------------
__global__ void k_build_P(const float* __restrict__ wd_emb, const float* __restrict__ E,
                          float* __restrict__ P)
{
    __shared__ float sE[7200];
    for (int i = threadIdx.x; i < 7200; i += blockDim.x) sE[i] = E[i];
    __syncthreads();
    const long total = (long)VV * 72;
    for (long idx = (long)blockIdx.x * blockDim.x + threadIdx.x; idx < total;
         idx += (long)gridDim.x * blockDim.x) {
        int r = (int)(idx % 72);
        long v = idx / 72;
        int dg = r % 18;
        int tt = r / 18;
        const float* emb = wd_emb + v * 100;
        const float* e = sE + dg * 400 + tt * 100;
        float acc = 0.f;
#pragma unroll
        for (int d = 0; d < 100; ++d) acc += emb[d] * e[d];
        P[idx] = acc;
    }
}

// ---------------------------------------------------------------------------
// 3. gx_wd0[b][l][dg] = sum_taps P[wd[b,l-2+t]][t][dg] + beff[dg]
// ---------------------------------------------------------------------------
__global__ void k_gather_wd(const int* __restrict__ wd, const float* __restrict__ P,
                            const float* __restrict__ beff, float* __restrict__ gx)
{
    int idx = blockIdx.x * blockDim.x + threadIdx.x;
    if (idx >= BB * LL * 18) return;
    int dg = idx % 18;
    int bl = idx / 18;
    int l = bl % LL;
    int b = bl / LL;
    const int* row = wd + b * LL;
    float acc = beff[dg];
#pragma unroll
    for (int tt = 0; tt < 4; ++tt) {
        int ll = l - 2 + tt;
        if (ll >= 0 && ll < LL) {
            int v = row[ll];
            acc += P[(long)v * 72 + tt * 18 + dg];
        }
    }
    gx[idx] = acc;
}

// ---------------------------------------------------------------------------
// 4. gx_pos0[b][l][dg] = Gp[pos[b,l]][dg]
// ---------------------------------------------------------------------------
__global__ void k_gather_pos(const int* __restrict__ pos, const float* __restrict__ Gp,
                             float* __restrict__ gx)
{
    int idx = blockIdx.x * blockDim.x + threadIdx.x;
    if (idx >= BB * LL * 18) return;
    int dg = idx % 18;
    int bl = idx / 18;
    int p = pos[bl];
    gx[idx] = Gp[p * 18 + dg];
}

// ---------------------------------------------------------------------------
// 5. GRU scan: 2048 chains = {branch(2) x dir(2) x b(512)}, one thread each.
//    gx layout (b, l, dg=dir*9+g); out layout (b, l, dir*3+i)
// ---------------------------------------------------------------------------
__global__ void k_scan(const float* __restrict__ gxA, const float* __restrict__ gxB,
                       float* __restrict__ outA, float* __restrict__ outB,
                       const float* __restrict__ whhA, const float* __restrict__ bhhA,
                       const float* __restrict__ whhB, const float* __restrict__ bhhB)
{
    int tid = blockIdx.x * blockDim.x + threadIdx.x;
    if (tid >= 2048) return;
    int branch = tid >> 10;
    int rem = tid & 1023;
    int dir = rem >> 9;
    int b = rem & 511;

    const float* gx = branch ? gxB : gxA;
    float* out = branch ? outB : outA;
    const float* whh = (branch ? whhB : whhA) + dir * 27;
    const float* bhh = (branch ? bhhB : bhhA) + dir * 9;

    float w[9][3], bb[9];
#pragma unroll
    for (int g = 0; g < 9; ++g) {
        bb[g] = bhh[g];
#pragma unroll
        for (int i = 0; i < 3; ++i) w[g][i] = whh[g * 3 + i];
    }

    float h0 = 0.f, h1 = 0.f, h2 = 0.f;
    const float* gbase = gx + (long)b * LL * 18 + dir * 9;
    float* obase = out + (long)b * LL * 6 + dir * 3;
    int l = dir ? (LL - 1) : 0;
    int step = dir ? -1 : 1;

    float g[9];
    {
        const float* p = gbase + l * 18;
#pragma unroll
        for (int k = 0; k < 9; ++k) g[k] = p[k];
    }
    for (int t = 0; t < LL; ++t) {
        float gn[9];
        bool more = (t < LL - 1);
        if (more) {
            const float* p = gbase + (l + step) * 18;
#pragma unroll
            for (int k = 0; k < 9; ++k) gn[k] = p[k];
        }
        float gh[9];
#pragma unroll
        for (int gg = 0; gg < 9; ++gg)
            gh[gg] = bb[gg] + w[gg][0] * h0 + w[gg][1] * h1 + w[gg][2] * h2;
        float r0 = sigm(g[0] + gh[0]), r1 = sigm(g[1] + gh[1]), r2 = sigm(g[2] + gh[2]);
        float z0 = sigm(g[3] + gh[3]), z1 = sigm(g[4] + gh[4]), z2 = sigm(g[5] + gh[5]);
        float n0 = tanh_(g[6] + r0 * gh[6]);
        float n1 = tanh_(g[7] + r1 * gh[7]);
        float n2 = tanh_(g[8] + r2 * gh[8]);
        h0 = n0 + z0 * (h0 - n0);
        h1 = n1 + z1 * (h1 - n1);
        h2 = n2 + z2 * (h2 - n2);
        float* o = obase + l * 6;
        o[0] = h0; o[1] = h1; o[2] = h2;
        if (more) {
#pragma unroll
            for (int k = 0; k < 9; ++k) g[k] = gn[k];
        }
        l += step;
    }
}

// ---------------------------------------------------------------------------
// 6. layer-1 input projection: gx1[b][l][dg] = out0[b][l][:6] . wih1[dg][:6] + bih1[dg]
// ---------------------------------------------------------------------------
__global__ void k_gx1(const float* __restrict__ out0A, const float* __restrict__ out0B,
                      const float* __restrict__ wih1A, const float* __restrict__ bih1A,
                      const float* __restrict__ wih1B, const float* __restrict__ bih1B,
                      float* __restrict__ gxA, float* __restrict__ gxB)
{
    long idx = (long)blockIdx.x * blockDim.x + threadIdx.x;
    const long tot = (long)BB * LL * 18;
    if (idx >= 2 * tot) return;
    int branch = idx >= tot;
    long k = branch ? (idx - tot) : idx;
    int dg = (int)(k % 18);
    long bl = k / 18;
    const float* row = (branch ? out0B : out0A) + bl * 6;
    const float* wih = (branch ? wih1B : wih1A) + dg * 6;
    const float* bih = branch ? bih1B : bih1A;
    float acc = bih[dg];
#pragma unroll
    for (int j = 0; j < 6; ++j) acc += row[j] * wih[j];
    (branch ? gxB : gxA)[k] = acc;
}

// ---------------------------------------------------------------------------
// 7. attention over wd_out: per-batch block (64 threads = 1 wave)
// ---------------------------------------------------------------------------
__global__ void k_atten(const float* __restrict__ out1A, const float* __restrict__ sw,
                        const float* __restrict__ ap, float* __restrict__ wd_atten)
{
    int b = blockIdx.x;
    int lane = threadIdx.x;
    __shared__ float ssw[36], sap[6];
    if (lane < 36) ssw[lane] = sw[lane];
    if (lane < 6) sap[lane] = ap[lane];
    __syncthreads();
    const float* base = out1A + (long)b * LL * 6;

    float att[8];
    float mx = -1e30f;
#pragma unroll
    for (int k = 0; k < 8; ++k) {
        int l = lane + 64 * k;
        const float* row = base + l * 6;
        float r0 = row[0], r1 = row[1], r2 = row[2], r3 = row[3], r4 = row[4], r5 = row[5];
        float a = 0.f;
#pragma unroll
        for (int j = 0; j < 6; ++j) {
            float s = r0 * ssw[0 * 6 + j] + r1 * ssw[1 * 6 + j] + r2 * ssw[2 * 6 + j] +
                      r3 * ssw[3 * 6 + j] + r4 * ssw[4 * 6 + j] + r5 * ssw[5 * 6 + j];
            a += sap[j] * tanh_(s);
        }
        att[k] = a;
        mx = fmaxf(mx, a);
    }
#pragma unroll
    for (int off = 32; off; off >>= 1) mx = fmaxf(mx, __shfl_xor(mx, off));
    float e[8];
    float sum = 0.f;
#pragma unroll
    for (int k = 0; k < 8; ++k) { e[k] = __expf(att[k] - mx); sum += e[k]; }
#pragma unroll
    for (int off = 32; off; off >>= 1) sum += __shfl_xor(sum, off);

    float acc[6] = {0.f, 0.f, 0.f, 0.f, 0.f, 0.f};
#pragma unroll
    for (int k = 0; k < 8; ++k) {
        int l = lane + 64 * k;
        const float* row = base + l * 6;
#pragma unroll
        for (int j = 0; j < 6; ++j) acc[j] += e[k] * row[j];
    }
#pragma unroll
    for (int j = 0; j < 6; ++j) {
#pragma unroll
        for (int off = 32; off; off >>= 1) acc[j] += __shfl_xor(acc[j], off);
    }
    if (lane == 0) {
#pragma unroll
        for (int j = 0; j < 6; ++j) wd_atten[b * 6 + j] = acc[j] / sum;
    }
}

// ---------------------------------------------------------------------------
// 8. tail: posfc -> auxi, concat, fc1 (BN, relu), fc2, softmax -> outputs
//    out layout: logits (B,6) flat first, then auxi (B,3)
// ---------------------------------------------------------------------------
__global__ void k_tail(const float* __restrict__ out1B, const float* __restrict__ wd_atten,
                       const float* __restrict__ pg, const float* __restrict__ pb,
                       const float* __restrict__ pw, const float* __restrict__ pbias,
                       const float* __restrict__ f1w, const float* __restrict__ f1b,
                       const float* __restrict__ fg, const float* __restrict__ fb,
                       const float* __restrict__ f2w, const float* __restrict__ f2b,
                       float* __restrict__ out)
{
    int b = blockIdx.x;
    int lane = threadIdx.x;
    __shared__ float sph[6], scomb[9], sh[128], sl[6], se[6];
    const float BN = 0.9999950000374997f; // 1/sqrt(1+1e-5)

    if (lane < 6) {
        float v = out1B[((long)b * LL + (LL - 1)) * 6 + lane];
        float x = v * BN * pg[lane] + pb[lane];
        sph[lane] = fmaxf(x, 0.f);
        scomb[lane] = wd_atten[b * 6 + lane];
    }
    __syncthreads();
    if (lane == 0) {
        float a[3];
#pragma unroll
        for (int j = 0; j < 3; ++j) {
            float t = pbias[j];
#pragma unroll
            for (int i = 0; i < 6; ++i) t += sph[i] * pw[j * 6 + i];
            a[j] = t;
        }
        float m = fmaxf(a[0], fmaxf(a[1], a[2]));
        float e0 = __expf(a[0] - m), e1 = __expf(a[1] - m), e2 = __expf(a[2] - m);
        float s = e0 + e1 + e2;
        float x0 = e0 / s, x1 = e1 / s, x2 = e2 / s;
        scomb[6] = x0; scomb[7] = x1; scomb[8] = x2;
        out[BB * 6 + b * 3 + 0] = x0;
        out[BB * 6 + b * 3 + 1] = x1;
        out[BB * 6 + b * 3 + 2] = x2;
    }
    __syncthreads();
    for (int o = lane; o < 128; o += 64) {
        float t = f1b[o];
#pragma unroll
        for (int k = 0; k < 9; ++k) t += scomb[k] * f1w[o * 9 + k];
        float x = t * BN * fg[o] + fb[o];
        sh[o] = fmaxf(x, 0.f);
    }
    __syncthreads();
    if (lane < 6) {
        float t = f2b[lane];
        for (int k = 0; k < 128; ++k) t += sh[k] * f2w[lane * 128 + k];
        sl[lane] = t;
    }
    __syncthreads();
    if (lane < 6) {
        float m = sl[0];
#pragma unroll
        for (int j = 1; j < 6; ++j) m = fmaxf(m, sl[j]);
        se[lane] = __expf(sl[lane] - m);
    }
    __syncthreads();
    if (lane < 6) {
        float s = se[0] + se[1] + se[2] + se[3] + se[4] + se[5];
        out[b * 6 + lane] = se[lane] / s;
    }
}

// ---------------------------------------------------------------------------
extern "C" void kernel_launch(void* const* d_in, const int* in_sizes, int n_in,
                              void* d_out, int out_size, void* d_ws, size_t ws_size,
                              hipStream_t stream)
{
    const int* wd  = (const int*)d_in[0];
    const int* pos = (const int*)d_in[1];
    const float* wd_emb  = (const float*)d_in[2];
    const float* pos_emb = (const float*)d_in[3];
    const float* cw2 = (const float*)d_in[4];  const float* cb2 = (const float*)d_in[5];
    const float* cw3 = (const float*)d_in[6];  const float* cb3 = (const float*)d_in[7];
    const float* cw4 = (const float*)d_in[8];  const float* cb4 = (const float*)d_in[9];
    const float* wd_wih0 = (const float*)d_in[10]; const float* wd_whh0 = (const float*)d_in[11];
    const float* wd_bih0 = (const float*)d_in[12]; const float* wd_bhh0 = (const float*)d_in[13];
    const float* wd_wih1 = (const float*)d_in[14]; const float* wd_whh1 = (const float*)d_in[15];
    const float* wd_bih1 = (const float*)d_in[16]; const float* wd_bhh1 = (const float*)d_in[17];
    const float* pos_wih0 = (const float*)d_in[18]; const float* pos_whh0 = (const float*)d_in[19];
    const float* pos_bih0 = (const float*)d_in[20]; const float* pos_bhh0 = (const float*)d_in[21];
    const float* pos_wih1 = (const float*)d_in[22]; const float* pos_whh1 = (const float*)d_in[23];
    const float* pos_bih1 = (const float*)d_in[24]; const float* pos_bhh1 = (const float*)d_in[25];
    const float* squish_w   = (const float*)d_in[26];
    const float* atten_proj = (const float*)d_in[27];
    const float* posfc_gamma = (const float*)d_in[28]; const float* posfc_beta = (const float*)d_in[29];
    const float* posfc_w = (const float*)d_in[30]; const float* posfc_b = (const float*)d_in[31];
    const float* fc1_w = (const float*)d_in[32]; const float* fc1_b = (const float*)d_in[33];
    const float* fc_gamma = (const float*)d_in[34]; const float* fc_beta = (const float*)d_in[35];
    const float* fc2_w = (const float*)d_in[36]; const float* fc2_b = (const float*)d_in[37];

    float* ws = (float*)d_ws;
    size_t off = 0;
    float* P = ws + off;     off += (size_t)VV * 72;       // 1,710,504
    float* gxA = ws + off;   off += (size_t)BB * LL * 18;  // 4,718,592
    float* gxB = ws + off;   off += (size_t)BB * LL * 18;
    float* out0A = ws + off; off += (size_t)BB * LL * 6;
    float* out0B = ws + off; off += (size_t)BB * LL * 6;
    float* out1A = ws + off; off += (size_t)BB * LL * 6;
    float* out1B = ws + off; off += (size_t)BB * LL * 6;
    float* Etab = ws + off;  off += 7200;
    float* beff = ws + off;  off += 32;
    float* Gp = ws + off;    off += PP * 18 + 14;
    float* wdat = ws + off;  off += BB * 6;

    const int NGX = BB * LL * 18;

    k_build_tables<<<(7218 + PP * 18 + 255) / 256, 256, 0, stream>>>(
        wd_wih0, wd_bih0, cw2, cb2, cw3, cb3, cw4, cb4, pos_emb, pos_wih0, pos_bih0,
        Etab, beff, Gp);
    k_build_P<<<1024, 256, 0, stream>>>(wd_emb, Etab, P);
    k_gather_wd<<<(NGX + 255) / 256, 256, 0, stream>>>(wd, P, beff, gxA);
    k_gather_pos<<<(NGX + 255) / 256, 256, 0, stream>>>(pos, Gp, gxB);
    k_scan<<<32, 64, 0, stream>>>(gxA, gxB, out0A, out0B, wd_whh0, wd_bhh0, pos_whh0, pos_bhh0);
    k_gx1<<<(2 * NGX + 255) / 256, 256, 0, stream>>>(out0A, out0B, wd_wih1, wd_bih1,
                                                     pos_wih1, pos_bih1, gxA, gxB);
    k_scan<<<32, 64, 0, stream>>>(gxA, gxB, out1A, out1B, wd_whh1, wd_bhh1, pos_whh1, pos_bhh1);
    k_atten<<<BB, 64, 0, stream>>>(out1A, squish_w, atten_proj, wdat);
    k_tail<<<BB, 64, 0, stream>>>(out1B, wdat, posfc_gamma, posfc_beta, posfc_w, posfc_b,
                                  fc1_w, fc1_b, fc_gamma, fc_beta, fc2_w, fc2_b, (float*)d_out);
}

// Round 3
// 249.551 us; speedup vs baseline: 2.0965x; 2.0965x over previous
//
#include <hip/hip_runtime.h>
#include <math.h>

#define BB 512   // batch
#define LL 512   // seq len
#define VV 23757 // wd vocab
#define PP 57    // pos vocab

__device__ __forceinline__ float rcp_(float x) { return __builtin_amdgcn_rcpf(x); }
__device__ __forceinline__ float sigm(float x) { return rcp_(1.f + __expf(-x)); }
__device__ __forceinline__ float tanh_(float x) { return 1.f - 2.f * rcp_(__expf(2.f * x) + 1.f); }

// quad_perm broadcast of lane K (0..2) within each 4-lane group, via DPP.
template <int K>
__device__ __forceinline__ float qb(float x) {
    constexpr int ctrl = K * 0x55; // [K,K,K,K] quad permute
    return __int_as_float(__builtin_amdgcn_update_dpp(0, __float_as_int(x), ctrl, 0xF, 0xF, true));
}

// ---------------------------------------------------------------------------
// 1. Tables: E (conv folded into wd wih0), beff, Gp (pos layer-0 gx table)
//    E layout: [dg(18)][tap(4)][d(100)]; tap t reads source position l-2+t.
// ---------------------------------------------------------------------------
__global__ void k_build_tables(const float* __restrict__ wd_wih0, const float* __restrict__ wd_bih0,
                               const float* __restrict__ cw2, const float* __restrict__ cb2,
                               const float* __restrict__ cw3, const float* __restrict__ cb3,
                               const float* __restrict__ cw4, const float* __restrict__ cb4,
                               const float* __restrict__ pos_emb,
                               const float* __restrict__ pos_wih0, const float* __restrict__ pos_bih0,
                               float* __restrict__ E, float* __restrict__ beff, float* __restrict__ Gp)
{
    int idx = blockIdx.x * blockDim.x + threadIdx.x;
    if (idx < 7200) {
        int d  = idx % 100;
        int tt = (idx / 100) % 4;
        int dg = idx / 400;
        const float* wih = wd_wih0 + dg * 144;
        float acc = 0.f;
        if (tt == 0) {        // offset -2
            for (int o = 0; o < 48; ++o) acc += wih[96 + o] * cw4[o * 400 + d * 4 + 0];
        } else if (tt == 1) { // offset -1
            for (int o = 0; o < 48; ++o) acc += wih[o]      * cw2[o * 200 + d * 2 + 0];
            for (int o = 0; o < 48; ++o) acc += wih[48 + o] * cw3[o * 300 + d * 3 + 0];
            for (int o = 0; o < 48; ++o) acc += wih[96 + o] * cw4[o * 400 + d * 4 + 1];
        } else if (tt == 2) { // offset 0
            for (int o = 0; o < 48; ++o) acc += wih[o]      * cw2[o * 200 + d * 2 + 1];
            for (int o = 0; o < 48; ++o) acc += wih[48 + o] * cw3[o * 300 + d * 3 + 1];
            for (int o = 0; o < 48; ++o) acc += wih[96 + o] * cw4[o * 400 + d * 4 + 2];
        } else {              // offset +1
            for (int o = 0; o < 48; ++o) acc += wih[48 + o] * cw3[o * 300 + d * 3 + 2];
            for (int o = 0; o < 48; ++o) acc += wih[96 + o] * cw4[o * 400 + d * 4 + 3];
        }
        E[idx] = acc;
    } else if (idx < 7218) {
        int dg = idx - 7200;
        float acc = wd_bih0[dg];
        for (int o = 0; o < 48; ++o) acc += wd_wih0[dg * 144 + o]      * cb2[o];
        for (int o = 0; o < 48; ++o) acc += wd_wih0[dg * 144 + 48 + o] * cb3[o];
        for (int o = 0; o < 48; ++o) acc += wd_wih0[dg * 144 + 96 + o] * cb4[o];
        beff[dg] = acc;
    } else if (idx < 7218 + PP * 18) {
        int k = idx - 7218;
        int dg = k % 18;
        int p  = k / 18;
        float acc = pos_bih0[dg];
        for (int d = 0; d < 100; ++d) acc += pos_emb[p * 100 + d] * pos_wih0[dg * 100 + d];
        Gp[p * 18 + dg] = acc;
    }
}

// ---------------------------------------------------------------------------
// 2. P[v][tap][dg(18)] = wd_emb[v,:] . E[dg][tap][:]
// ---------------------------------------------------------------------------
__global__ void k_build_P(const float* __restrict__ wd_emb, const float* __restrict__ E,
                          float* __restrict__ P)
{
    __shared__ float sE[7200];
    for (int i = threadIdx.x; i < 7200; i += blockDim.x) sE[i] = E[i];
    __syncthreads();
    const long total = (long)VV * 72;
    for (long idx = (long)blockIdx.x * blockDim.x + threadIdx.x; idx < total;
         idx += (long)gridDim.x * blockDim.x) {
        int r = (int)(idx % 72);
        long v = idx / 72;
        int dg = r % 18;
        int tt = r / 18;
        const float* emb = wd_emb + v * 100;
        const float* e = sE + dg * 400 + tt * 100;
        float acc = 0.f;
#pragma unroll
        for (int d = 0; d < 100; ++d) acc += emb[d] * e[d];
        P[idx] = acc;
    }
}

// ---------------------------------------------------------------------------
// 3. Fused gathers -> scan-layout gx: [dir][b][l][unit j][gate r,z,n]
//    wd branch:  gxA[...] = beff[dg] + sum_t P[wd[b,l-2+t]*72 + t*18 + dg]
//    pos branch: gxB[...] = Gp[pos[b,l]*18 + dg],  dg = dir*9 + g*3 + j
// ---------------------------------------------------------------------------
__global__ void k_gather(const int* __restrict__ wd, const int* __restrict__ pos,
                         const float* __restrict__ P, const float* __restrict__ beff,
                         const float* __restrict__ Gp,
                         float* __restrict__ gxA, float* __restrict__ gxB)
{
    const int NB = 2 * BB * LL * 9;
    int idx = blockIdx.x * blockDim.x + threadIdx.x;
    if (idx < NB) {
        int e = idx % 9;
        int g = e % 3, j = e / 3;
        int rest = idx / 9;
        int l = rest % LL;
        int b = (rest / LL) % BB;
        int dir = rest / (LL * BB);
        int dg = dir * 9 + g * 3 + j;
        const int* row = wd + b * LL;
        float acc = beff[dg];
#pragma unroll
        for (int tt = 0; tt < 4; ++tt) {
            int ll = l - 2 + tt;
            if (ll >= 0 && ll < LL) {
                int v = row[ll];
                acc += P[(long)v * 72 + tt * 18 + dg];
            }
        }
        gxA[idx] = acc;
    } else if (idx < 2 * NB) {
        int k = idx - NB;
        int e = k % 9;
        int g = e % 3, j = e / 3;
        int rest = k / 9;
        int l = rest % LL;
        int b = (rest / LL) % BB;
        int dir = rest / (LL * BB);
        int dg = dir * 9 + g * 3 + j;
        int p = pos[b * LL + l];
        gxB[k] = Gp[p * 18 + dg];
    }
}

// ---------------------------------------------------------------------------
// 4. GRU scan: 4 lanes per chain (lane j = hidden unit j, lane 3 mirrors 2).
//    2048 chains x 4 = 8192 threads = 128 one-wave blocks.
//    gx layout: [dir][b][l][j][3] (9 floats per (dir,b,l));
//    out layout: [b][l][dir*3+j].
// ---------------------------------------------------------------------------
__global__ void __launch_bounds__(64) k_scan(
        const float* __restrict__ gxA, const float* __restrict__ gxB,
        float* __restrict__ outA, float* __restrict__ outB,
        const float* __restrict__ whhA, const float* __restrict__ bhhA,
        const float* __restrict__ whhB, const float* __restrict__ bhhB)
{
    int tid = blockIdx.x * 64 + threadIdx.x;
    int chain = tid >> 2;
    int sub = tid & 3;
    int jj = sub < 3 ? sub : 2;
    int branch = chain >> 10;
    int rem = chain & 1023;
    int dir = rem >> 9;
    int b = rem & 511;

    const float* gx = branch ? gxB : gxA;
    float* out = branch ? outB : outA;
    const float* whh = (branch ? whhB : whhA) + dir * 27;
    const float* bhh = (branch ? bhhB : bhhA) + dir * 9;

    // lane's rows: r=jj, z=3+jj, n=6+jj
    float wr0 = whh[jj * 3 + 0], wr1 = whh[jj * 3 + 1], wr2 = whh[jj * 3 + 2];
    float wz0 = whh[(3 + jj) * 3 + 0], wz1 = whh[(3 + jj) * 3 + 1], wz2 = whh[(3 + jj) * 3 + 2];
    float wn0 = whh[(6 + jj) * 3 + 0], wn1 = whh[(6 + jj) * 3 + 1], wn2 = whh[(6 + jj) * 3 + 2];
    float br = bhh[jj], bz = bhh[3 + jj], bn = bhh[6 + jj];

    // step t -> l = dir ? 511-t : t ; address p0 + t*stp
    const float* p0 = gx + ((long)(dir * BB + b) * LL + (dir ? (LL - 1) : 0)) * 9 + jj * 3;
    long stp = dir ? -9 : 9;
    float* ob = out + (long)b * LL * 6 + dir * 3 + jj;
    int l = dir ? (LL - 1) : 0;
    int lstep = dir ? -1 : 1;

    float buf[8][3];
#pragma unroll
    for (int s = 0; s < 8; ++s) {
        const float* p = p0 + (long)s * stp;
        buf[s][0] = p[0]; buf[s][1] = p[1]; buf[s][2] = p[2];
    }

    float h = 0.f;
    bool active = (sub < 3);
    for (int blk = 0; blk < 64; ++blk) {
#pragma unroll
        for (int s = 0; s < 8; ++s) {
            int t = blk * 8 + s;
            float gr = buf[s][0], gz = buf[s][1], gn = buf[s][2];
            // issue prefetch for step t+8 into this slot (clamped address; value
            // only consumed when valid)
            int tf = t + 8; if (tf > LL - 1) tf = LL - 1;
            const float* pf = p0 + (long)tf * stp;
            buf[s][0] = pf[0]; buf[s][1] = pf[1]; buf[s][2] = pf[2];

            float h0 = qb<0>(h), h1 = qb<1>(h), h2 = qb<2>(h);
            float ghr = br + wr0 * h0 + wr1 * h1 + wr2 * h2;
            float ghz = bz + wz0 * h0 + wz1 * h1 + wz2 * h2;
            float ghn = bn + wn0 * h0 + wn1 * h1 + wn2 * h2;
            float r = sigm(gr + ghr);
            float z = sigm(gz + ghz);
            float n = tanh_(gn + r * ghn);
            h = n + z * (h - n);
            if (active) ob[l * 6] = h;
            l += lstep;
        }
    }
}

// ---------------------------------------------------------------------------
// 5. layer-1 gx: gx1[branch][dir][b][l][j][g] = out0[b][l][:6].wih1[dg] + bih1[dg]
// ---------------------------------------------------------------------------
__global__ void k_gx1(const float* __restrict__ out0A, const float* __restrict__ out0B,
                      const float* __restrict__ wih1A, const float* __restrict__ bih1A,
                      const float* __restrict__ wih1B, const float* __restrict__ bih1B,
                      float* __restrict__ gxA, float* __restrict__ gxB)
{
    const int NB = 2 * BB * LL * 9;
    int idx = blockIdx.x * blockDim.x + threadIdx.x;
    if (idx >= 2 * NB) return;
    int branch = idx >= NB;
    int k = branch ? (idx - NB) : idx;
    int e = k % 9;
    int g = e % 3, j = e / 3;
    int rest = k / 9;
    int l = rest % LL;
    int b = (rest / LL) % BB;
    int dir = rest / (LL * BB);
    int dg = dir * 9 + g * 3 + j;
    const float* row = (branch ? out0B : out0A) + ((long)b * LL + l) * 6;
    const float* wih = (branch ? wih1B : wih1A) + dg * 6;
    float acc = (branch ? bih1B : bih1A)[dg];
#pragma unroll
    for (int c = 0; c < 6; ++c) acc += row[c] * wih[c];
    (branch ? gxB : gxA)[k] = acc;
}

// ---------------------------------------------------------------------------
// 6. attention over wd_out
// ---------------------------------------------------------------------------
__global__ void k_atten(const float* __restrict__ out1A, const float* __restrict__ sw,
                        const float* __restrict__ ap, float* __restrict__ wd_atten)
{
    int b = blockIdx.x;
    int lane = threadIdx.x;
    __shared__ float ssw[36], sap[6];
    if (lane < 36) ssw[lane] = sw[lane];
    if (lane < 6) sap[lane] = ap[lane];
    __syncthreads();
    const float* base = out1A + (long)b * LL * 6;

    float att[8];
    float mx = -1e30f;
#pragma unroll
    for (int k = 0; k < 8; ++k) {
        int l = lane + 64 * k;
        const float* row = base + l * 6;
        float r0 = row[0], r1 = row[1], r2 = row[2], r3 = row[3], r4 = row[4], r5 = row[5];
        float a = 0.f;
#pragma unroll
        for (int j = 0; j < 6; ++j) {
            float s = r0 * ssw[0 * 6 + j] + r1 * ssw[1 * 6 + j] + r2 * ssw[2 * 6 + j] +
                      r3 * ssw[3 * 6 + j] + r4 * ssw[4 * 6 + j] + r5 * ssw[5 * 6 + j];
            a += sap[j] * tanh_(s);
        }
        att[k] = a;
        mx = fmaxf(mx, a);
    }
#pragma unroll
    for (int off = 32; off; off >>= 1) mx = fmaxf(mx, __shfl_xor(mx, off));
    float e[8];
    float sum = 0.f;
#pragma unroll
    for (int k = 0; k < 8; ++k) { e[k] = __expf(att[k] - mx); sum += e[k]; }
#pragma unroll
    for (int off = 32; off; off >>= 1) sum += __shfl_xor(sum, off);

    float acc[6] = {0.f, 0.f, 0.f, 0.f, 0.f, 0.f};
#pragma unroll
    for (int k = 0; k < 8; ++k) {
        int l = lane + 64 * k;
        const float* row = base + l * 6;
#pragma unroll
        for (int j = 0; j < 6; ++j) acc[j] += e[k] * row[j];
    }
#pragma unroll
    for (int j = 0; j < 6; ++j) {
#pragma unroll
        for (int off = 32; off; off >>= 1) acc[j] += __shfl_xor(acc[j], off);
    }
    if (lane == 0) {
#pragma unroll
        for (int j = 0; j < 6; ++j) wd_atten[b * 6 + j] = acc[j] / sum;
    }
}

// ---------------------------------------------------------------------------
// 7. tail: posfc -> auxi, concat, fc1(BN,relu), fc2, softmax
// ---------------------------------------------------------------------------
__global__ void k_tail(const float* __restrict__ out1B, const float* __restrict__ wd_atten,
                       const float* __restrict__ pg, const float* __restrict__ pb,
                       const float* __restrict__ pw, const float* __restrict__ pbias,
                       const float* __restrict__ f1w, const float* __restrict__ f1b,
                       const float* __restrict__ fg, const float* __restrict__ fb,
                       const float* __restrict__ f2w, const float* __restrict__ f2b,
                       float* __restrict__ out)
{
    int b = blockIdx.x;
    int lane = threadIdx.x;
    __shared__ float sph[6], scomb[9], sh[128], sl[6], se[6];
    const float BN = 0.9999950000374997f; // 1/sqrt(1+1e-5)

    if (lane < 6) {
        float v = out1B[((long)b * LL + (LL - 1)) * 6 + lane];
        float x = v * BN * pg[lane] + pb[lane];
        sph[lane] = fmaxf(x, 0.f);
        scomb[lane] = wd_atten[b * 6 + lane];
    }
    __syncthreads();
    if (lane == 0) {
        float a[3];
#pragma unroll
        for (int j = 0; j < 3; ++j) {
            float t = pbias[j];
#pragma unroll
            for (int i = 0; i < 6; ++i) t += sph[i] * pw[j * 6 + i];
            a[j] = t;
        }
        float m = fmaxf(a[0], fmaxf(a[1], a[2]));
        float e0 = __expf(a[0] - m), e1 = __expf(a[1] - m), e2 = __expf(a[2] - m);
        float s = e0 + e1 + e2;
        float x0 = e0 / s, x1 = e1 / s, x2 = e2 / s;
        scomb[6] = x0; scomb[7] = x1; scomb[8] = x2;
        out[BB * 6 + b * 3 + 0] = x0;
        out[BB * 6 + b * 3 + 1] = x1;
        out[BB * 6 + b * 3 + 2] = x2;
    }
    __syncthreads();
    for (int o = lane; o < 128; o += 64) {
        float t = f1b[o];
#pragma unroll
        for (int k = 0; k < 9; ++k) t += scomb[k] * f1w[o * 9 + k];
        float x = t * BN * fg[o] + fb[o];
        sh[o] = fmaxf(x, 0.f);
    }
    __syncthreads();
    if (lane < 6) {
        float t = f2b[lane];
        for (int k = 0; k < 128; ++k) t += sh[k] * f2w[lane * 128 + k];
        sl[lane] = t;
    }
    __syncthreads();
    if (lane < 6) {
        float m = sl[0];
#pragma unroll
        for (int j = 1; j < 6; ++j) m = fmaxf(m, sl[j]);
        se[lane] = __expf(sl[lane] - m);
    }
    __syncthreads();
    if (lane < 6) {
        float s = se[0] + se[1] + se[2] + se[3] + se[4] + se[5];
        out[b * 6 + lane] = se[lane] / s;
    }
}

// ---------------------------------------------------------------------------
extern "C" void kernel_launch(void* const* d_in, const int* in_sizes, int n_in,
                              void* d_out, int out_size, void* d_ws, size_t ws_size,
                              hipStream_t stream)
{
    const int* wd  = (const int*)d_in[0];
    const int* pos = (const int*)d_in[1];
    const float* wd_emb  = (const float*)d_in[2];
    const float* cw2 = (const float*)d_in[4];  const float* cb2 = (const float*)d_in[5];
    const float* cw3 = (const float*)d_in[6];  const float* cb3 = (const float*)d_in[7];
    const float* cw4 = (const float*)d_in[8];  const float* cb4 = (const float*)d_in[9];
    const float* pos_emb = (const float*)d_in[3];
    const float* wd_wih0 = (const float*)d_in[10]; const float* wd_whh0 = (const float*)d_in[11];
    const float* wd_bih0 = (const float*)d_in[12]; const float* wd_bhh0 = (const float*)d_in[13];
    const float* wd_wih1 = (const float*)d_in[14]; const float* wd_whh1 = (const float*)d_in[15];
    const float* wd_bih1 = (const float*)d_in[16]; const float* wd_bhh1 = (const float*)d_in[17];
    const float* pos_wih0 = (const float*)d_in[18]; const float* pos_whh0 = (const float*)d_in[19];
    const float* pos_bih0 = (const float*)d_in[20]; const float* pos_bhh0 = (const float*)d_in[21];
    const float* pos_wih1 = (const float*)d_in[22]; const float* pos_whh1 = (const float*)d_in[23];
    const float* pos_bih1 = (const float*)d_in[24]; const float* pos_bhh1 = (const float*)d_in[25];
    const float* squish_w   = (const float*)d_in[26];
    const float* atten_proj = (const float*)d_in[27];
    const float* posfc_gamma = (const float*)d_in[28]; const float* posfc_beta = (const float*)d_in[29];
    const float* posfc_w = (const float*)d_in[30]; const float* posfc_b = (const float*)d_in[31];
    const float* fc1_w = (const float*)d_in[32]; const float* fc1_b = (const float*)d_in[33];
    const float* fc_gamma = (const float*)d_in[34]; const float* fc_beta = (const float*)d_in[35];
    const float* fc2_w = (const float*)d_in[36]; const float* fc2_b = (const float*)d_in[37];

    float* ws = (float*)d_ws;
    size_t off = 0;
    float* P = ws + off;     off += (size_t)VV * 72;          // 1,710,504
    float* gxA = ws + off;   off += (size_t)2 * BB * LL * 9;  // 4,718,592
    float* gxB = ws + off;   off += (size_t)2 * BB * LL * 9;
    float* out0A = ws + off; off += (size_t)BB * LL * 6;
    float* out0B = ws + off; off += (size_t)BB * LL * 6;
    float* out1A = ws + off; off += (size_t)BB * LL * 6;
    float* out1B = ws + off; off += (size_t)BB * LL * 6;
    float* Etab = ws + off;  off += 7200;
    float* beff = ws + off;  off += 32;
    float* Gp = ws + off;    off += PP * 18 + 14;
    float* wdat = ws + off;  off += BB * 6;

    const int NB = 2 * BB * LL * 9;

    k_build_tables<<<(7218 + PP * 18 + 255) / 256, 256, 0, stream>>>(
        wd_wih0, wd_bih0, cw2, cb2, cw3, cb3, cw4, cb4, pos_emb, pos_wih0, pos_bih0,
        Etab, beff, Gp);
    k_build_P<<<1024, 256, 0, stream>>>(wd_emb, Etab, P);
    k_gather<<<(2 * NB + 255) / 256, 256, 0, stream>>>(wd, pos, P, beff, Gp, gxA, gxB);
    k_scan<<<128, 64, 0, stream>>>(gxA, gxB, out0A, out0B, wd_whh0, wd_bhh0, pos_whh0, pos_bhh0);
    k_gx1<<<(2 * NB + 255) / 256, 256, 0, stream>>>(out0A, out0B, wd_wih1, wd_bih1,
                                                    pos_wih1, pos_bih1, gxA, gxB);
    k_scan<<<128, 64, 0, stream>>>(gxA, gxB, out1A, out1B, wd_whh1, wd_bhh1, pos_whh1, pos_bhh1);
    k_atten<<<BB, 64, 0, stream>>>(out1A, squish_w, atten_proj, wdat);
    k_tail<<<BB, 64, 0, stream>>>(out1B, wdat, posfc_gamma, posfc_beta, posfc_w, posfc_b,
                                  fc1_w, fc1_b, fc_gamma, fc_beta, fc2_w, fc2_b, (float*)d_out);
}

// Round 4
// 208.815 us; speedup vs baseline: 2.5055x; 1.1951x over previous
//
#include <hip/hip_runtime.h>
#include <math.h>

#define BB 512   // batch
#define LL 512   // seq len
#define VV 23757 // wd vocab
#define PP 57    // pos vocab

#define L2E  1.4426950408889634f
#define NL2E (-1.4426950408889634f)
#define TL2E 2.8853900817779268f   // 2*log2(e)

__device__ __forceinline__ float rcp_(float x) { return __builtin_amdgcn_rcpf(x); }
__device__ __forceinline__ float exp2_(float x) { return __builtin_amdgcn_exp2f(x); }
__device__ __forceinline__ float tanh_(float x) { return 1.f - 2.f * rcp_(exp2_(TL2E * x) + 1.f); }

// gate scale: r,z -> -log2e ; n -> 2*log2e   (dg = dir*9 + g*3 + j)
__device__ __forceinline__ float gscale(int dg) {
    int g = (dg % 9) / 3;
    return g == 2 ? TL2E : NL2E;
}
__device__ __forceinline__ int is_rz(int dg) { return ((dg % 9) / 3) < 2; }

// quad_perm broadcast of lane K (0..2) within each 4-lane group, via DPP.
template <int K>
__device__ __forceinline__ float qb(float x) {
    constexpr int ctrl = K * 0x55;
    return __int_as_float(__builtin_amdgcn_update_dpp(0, __float_as_int(x), ctrl, 0xF, 0xF, true));
}

struct F3 { float r, z, n; };

// ---------------------------------------------------------------------------
// 1. Tables.
//  [0,7200)      E[dg][tap][d] (raw conv-folded wd wih0)
//  [7200,7218)   beff~[dg]  = s_g*(conv-bias-fold + bih + (rz? bhh0 : 0))
//  [7218,8244)   Gp~[p][dg] = s_g*(pos_emb[p].wih0[dg] + bih + (rz? bhh0 : 0))
//  [8244,8352)   wd  wih1~[dg][c] = s_g*wih1
//  [8352,8370)   wd  bih1~[dg]    = s_g*(bih1 + (rz? bhh1:0))
//  [8370,8478)   pos wih1~
//  [8478,8496)   pos bih1~
// ---------------------------------------------------------------------------
__global__ void k_build_tables(const float* __restrict__ wd_wih0, const float* __restrict__ wd_bih0,
                               const float* __restrict__ wd_bhh0,
                               const float* __restrict__ cw2, const float* __restrict__ cb2,
                               const float* __restrict__ cw3, const float* __restrict__ cb3,
                               const float* __restrict__ cw4, const float* __restrict__ cb4,
                               const float* __restrict__ pos_emb,
                               const float* __restrict__ pos_wih0, const float* __restrict__ pos_bih0,
                               const float* __restrict__ pos_bhh0,
                               const float* __restrict__ wd_wih1, const float* __restrict__ wd_bih1,
                               const float* __restrict__ wd_bhh1,
                               const float* __restrict__ pos_wih1, const float* __restrict__ pos_bih1,
                               const float* __restrict__ pos_bhh1,
                               float* __restrict__ E, float* __restrict__ beff, float* __restrict__ Gp,
                               float* __restrict__ wih1t, float* __restrict__ bih1t)
{
    int idx = blockIdx.x * blockDim.x + threadIdx.x;
    if (idx < 7200) {
        int d  = idx % 100;
        int tt = (idx / 100) % 4;
        int dg = idx / 400;
        const float* wih = wd_wih0 + dg * 144;
        float acc = 0.f;
        if (tt == 0) {        // offset -2
            for (int o = 0; o < 48; ++o) acc += wih[96 + o] * cw4[o * 400 + d * 4 + 0];
        } else if (tt == 1) { // offset -1
            for (int o = 0; o < 48; ++o) acc += wih[o]      * cw2[o * 200 + d * 2 + 0];
            for (int o = 0; o < 48; ++o) acc += wih[48 + o] * cw3[o * 300 + d * 3 + 0];
            for (int o = 0; o < 48; ++o) acc += wih[96 + o] * cw4[o * 400 + d * 4 + 1];
        } else if (tt == 2) { // offset 0
            for (int o = 0; o < 48; ++o) acc += wih[o]      * cw2[o * 200 + d * 2 + 1];
            for (int o = 0; o < 48; ++o) acc += wih[48 + o] * cw3[o * 300 + d * 3 + 1];
            for (int o = 0; o < 48; ++o) acc += wih[96 + o] * cw4[o * 400 + d * 4 + 2];
        } else {              // offset +1
            for (int o = 0; o < 48; ++o) acc += wih[48 + o] * cw3[o * 300 + d * 3 + 2];
            for (int o = 0; o < 48; ++o) acc += wih[96 + o] * cw4[o * 400 + d * 4 + 3];
        }
        E[idx] = acc;
    } else if (idx < 7218) {
        int dg = idx - 7200;
        float acc = wd_bih0[dg];
        for (int o = 0; o < 48; ++o) acc += wd_wih0[dg * 144 + o]      * cb2[o];
        for (int o = 0; o < 48; ++o) acc += wd_wih0[dg * 144 + 48 + o] * cb3[o];
        for (int o = 0; o < 48; ++o) acc += wd_wih0[dg * 144 + 96 + o] * cb4[o];
        if (is_rz(dg)) acc += wd_bhh0[dg];
        beff[dg] = gscale(dg) * acc;
    } else if (idx < 8244) {
        int k = idx - 7218;
        int dg = k % 18;
        int p  = k / 18;
        float acc = pos_bih0[dg];
        for (int d = 0; d < 100; ++d) acc += pos_emb[p * 100 + d] * pos_wih0[dg * 100 + d];
        if (is_rz(dg)) acc += pos_bhh0[dg];
        Gp[p * 18 + dg] = gscale(dg) * acc;
    } else if (idx < 8352) {
        int i = idx - 8244; int dg = i / 6;
        wih1t[i] = gscale(dg) * wd_wih1[i];
    } else if (idx < 8370) {
        int dg = idx - 8352;
        float a = wd_bih1[dg] + (is_rz(dg) ? wd_bhh1[dg] : 0.f);
        bih1t[dg] = gscale(dg) * a;
    } else if (idx < 8478) {
        int i = idx - 8370; int dg = i / 6;
        wih1t[108 + i] = gscale(dg) * pos_wih1[i];
    } else if (idx < 8496) {
        int dg = idx - 8478;
        float a = pos_bih1[dg] + (is_rz(dg) ? pos_bhh1[dg] : 0.f);
        bih1t[18 + dg] = gscale(dg) * a;
    }
}

// ---------------------------------------------------------------------------
// 2. P~[v][tap][dg] = s_g * (wd_emb[v,:] . E[dg][tap][:])
// ---------------------------------------------------------------------------
__global__ void k_build_P(const float* __restrict__ wd_emb, const float* __restrict__ E,
                          float* __restrict__ P)
{
    __shared__ float sE[7200];
    for (int i = threadIdx.x; i < 7200; i += blockDim.x) sE[i] = E[i];
    __syncthreads();
    const long total = (long)VV * 72;
    for (long idx = (long)blockIdx.x * blockDim.x + threadIdx.x; idx < total;
         idx += (long)gridDim.x * blockDim.x) {
        int r = (int)(idx % 72);
        long v = idx / 72;
        int dg = r % 18;
        int tt = r / 18;
        const float* emb = wd_emb + v * 100;
        const float* e = sE + dg * 400 + tt * 100;
        float acc = 0.f;
#pragma unroll
        for (int d = 0; d < 100; ++d) acc += emb[d] * e[d];
        P[idx] = gscale(dg) * acc;
    }
}

// ---------------------------------------------------------------------------
// 3. Gather: one thread per (branch,b,l), all 18 gates, prescaled already.
//    gx layout: [(branch*2+dir)*BB + b][l][j][g]  (9 floats / (chain,l))
// ---------------------------------------------------------------------------
__global__ void k_gather(const int* __restrict__ wd, const int* __restrict__ pos,
                         const float* __restrict__ P, const float* __restrict__ beff,
                         const float* __restrict__ Gp, float* __restrict__ gx)
{
    int idx = blockIdx.x * blockDim.x + threadIdx.x;
    if (idx >= 2 * BB * LL) return;
    int branch = idx >= BB * LL;
    int k = idx - branch * BB * LL;
    int l = k % LL, b = k / LL;

    float v[18];
    if (!branch) {
#pragma unroll
        for (int i = 0; i < 18; ++i) v[i] = beff[i];
        const int* row = wd + b * LL;
#pragma unroll
        for (int t = 0; t < 4; ++t) {
            int ll = l - 2 + t;
            if (ll >= 0 && ll < LL) {
                const float* p = P + (long)row[ll] * 72 + t * 18;
#pragma unroll
                for (int i = 0; i < 18; ++i) v[i] += p[i];
            }
        }
    } else {
        const float* p = Gp + pos[k] * 18;
#pragma unroll
        for (int i = 0; i < 18; ++i) v[i] = p[i];
    }
    long base0 = ((long)(branch * 2 + 0) * BB + b) * (LL * 9) + l * 9;
    long base1 = ((long)(branch * 2 + 1) * BB + b) * (LL * 9) + l * 9;
#pragma unroll
    for (int j = 0; j < 3; ++j)
#pragma unroll
        for (int g = 0; g < 3; ++g) {
            gx[base0 + j * 3 + g] = v[g * 3 + j];
            gx[base1 + j * 3 + g] = v[9 + g * 3 + j];
        }
}

// ---------------------------------------------------------------------------
// 4. GRU scan. 4 lanes/chain; gates in exp2 form; LDS-staged coalesced output.
//    out layout: [(branch*2+dir)*BB + b][l][4]  (padded float4 per step)
// ---------------------------------------------------------------------------
__global__ void __launch_bounds__(64) k_scan(
        const float* __restrict__ gx0, float* __restrict__ out,
        const float* __restrict__ whhA, const float* __restrict__ bhhA,
        const float* __restrict__ whhB, const float* __restrict__ bhhB)
{
    __shared__ float lbuf[16 * 81];
    int lane = threadIdx.x;
    int c = lane >> 2, sub = lane & 3;
    int jj = sub < 3 ? sub : 2;
    int chain = blockIdx.x * 16 + c;
    int branch = chain >> 10;
    int rem = chain & 1023;
    int dir = rem >> 9;
    int b = rem & 511;

    const float* whh = (branch ? whhB : whhA) + dir * 27;
    const float* bhh = (branch ? bhhB : bhhA) + dir * 9;

    float wr0 = NL2E * whh[jj * 3 + 0], wr1 = NL2E * whh[jj * 3 + 1], wr2 = NL2E * whh[jj * 3 + 2];
    float wz0 = NL2E * whh[(3 + jj) * 3 + 0], wz1 = NL2E * whh[(3 + jj) * 3 + 1], wz2 = NL2E * whh[(3 + jj) * 3 + 2];
    float wn0 = TL2E * whh[(6 + jj) * 3 + 0], wn1 = TL2E * whh[(6 + jj) * 3 + 1], wn2 = TL2E * whh[(6 + jj) * 3 + 2];
    float bnx = TL2E * bhh[6 + jj];

    // byte offsets into gx
    int rowbase = ((branch * 2 + dir) * BB + b) * (LL * 36);
    int omin = rowbase + jj * 12;
    int omax = rowbase + 511 * 36 + jj * 12;
    int sstp = dir ? -36 : 36;
    int start = dir ? omax : omin;

    const char* gxc = (const char*)gx0;
    F3 buf[16];
#pragma unroll
    for (int s = 0; s < 16; ++s)
        buf[s] = *(const F3*)(gxc + (start + s * sstp));
    int opf = start + 16 * sstp;

    char* ob = (char*)out + (size_t)((branch * 2 + dir) * BB + b) * (LL * 16) + (sub * 64);
    int wa = c * 5 + sub; // LDS word slot base

    float h = 0.f;
    for (int blk = 0; blk < 32; ++blk) {
#pragma unroll
        for (int s = 0; s < 16; ++s) {
            F3 gv = buf[s];
            buf[s] = *(const F3*)(gxc + opf);
            int on = opf + sstp;
            on = on < omin ? omin : on;
            opf = on > omax ? omax : on;

            float h0 = qb<0>(h), h1 = qb<1>(h), h2 = qb<2>(h);
            float hm1 = h - 1.f;
            float sr = fmaf(wr0, h0, gv.r) + fmaf(wr1, h1, wr2 * h2);
            float sz = fmaf(wz0, h0, gv.z) + fmaf(wz1, h1, wz2 * h2);
            float gn3 = fmaf(wn0, h0, fmaf(wn1, h1, fmaf(wn2, h2, bnx)));
            float r = rcp_(1.f + exp2_(sr));
            float z = rcp_(1.f + exp2_(sz));
            float y2 = fmaf(r, gn3, gv.n);
            float u = rcp_(1.f + exp2_(y2));
            float a = fmaf(2.f, u, hm1);
            float n = fmaf(-2.f, u, 1.f);
            h = fmaf(z, a, n);
            lbuf[s * 81 + wa] = h;
        }
        __syncthreads();
        int l0 = dir ? (496 - blk * 16) : blk * 16;
#pragma unroll
        for (int i = 0; i < 4; ++i) {
            int lofs = sub * 4 + i;
            int s = dir ? (15 - lofs) : lofs;
            float4 vv;
            vv.x = lbuf[s * 81 + c * 5 + 0];
            vv.y = lbuf[s * 81 + c * 5 + 1];
            vv.z = lbuf[s * 81 + c * 5 + 2];
            vv.w = lbuf[s * 81 + c * 5 + 3];
            *(float4*)(ob + (size_t)l0 * 16 + i * 16) = vv;
        }
        __syncthreads();
    }
}

// ---------------------------------------------------------------------------
// 5. layer-1 gx: one thread per (branch,b,l); all 18 gates, prescaled tables.
// ---------------------------------------------------------------------------
__global__ void k_gx1(const float* __restrict__ out0,
                      const float* __restrict__ wih1t, const float* __restrict__ bih1t,
                      float* __restrict__ gx)
{
    int idx = blockIdx.x * blockDim.x + threadIdx.x;
    if (idx >= 2 * BB * LL) return;
    int branch = idx >= BB * LL;
    int k = idx - branch * BB * LL;
    int l = k % LL, b = k / LL;

    const float4 f4 = *(const float4*)(out0 + ((size_t)((branch * 2 + 0) * BB + b) * LL + l) * 4);
    const float4 b4 = *(const float4*)(out0 + ((size_t)((branch * 2 + 1) * BB + b) * LL + l) * 4);
    float row[6] = {f4.x, f4.y, f4.z, b4.x, b4.y, b4.z};
    const float* W = wih1t + branch * 108;
    const float* Bv = bih1t + branch * 18;

    float v[18];
#pragma unroll
    for (int dg = 0; dg < 18; ++dg) {
        float acc = Bv[dg];
#pragma unroll
        for (int cix = 0; cix < 6; ++cix) acc += row[cix] * W[dg * 6 + cix];
        v[dg] = acc;
    }
    long base0 = ((long)(branch * 2 + 0) * BB + b) * (LL * 9) + l * 9;
    long base1 = ((long)(branch * 2 + 1) * BB + b) * (LL * 9) + l * 9;
#pragma unroll
    for (int j = 0; j < 3; ++j)
#pragma unroll
        for (int g = 0; g < 3; ++g) {
            gx[base0 + j * 3 + g] = v[g * 3 + j];
            gx[base1 + j * 3 + g] = v[9 + g * 3 + j];
        }
}

// ---------------------------------------------------------------------------
// 6. attention over wd_out (out1 layout [dir-block][b][l][4])
// ---------------------------------------------------------------------------
__global__ void k_atten(const float* __restrict__ out1, const float* __restrict__ sw,
                        const float* __restrict__ ap, float* __restrict__ wd_atten)
{
    int b = blockIdx.x;
    int lane = threadIdx.x;
    __shared__ float ssw[36], sap[6];
    if (lane < 36) ssw[lane] = sw[lane];
    if (lane < 6) sap[lane] = ap[lane];
    __syncthreads();
    const float* F = out1 + (size_t)b * LL * 4;               // wd fwd
    const float* Bw = out1 + (size_t)(BB + b) * LL * 4;       // wd bwd

    float att[8];
    float mx = -1e30f;
#pragma unroll
    for (int k = 0; k < 8; ++k) {
        int l = lane + 64 * k;
        float4 f4 = *(const float4*)(F + l * 4);
        float4 b4 = *(const float4*)(Bw + l * 4);
        float r0 = f4.x, r1 = f4.y, r2 = f4.z, r3 = b4.x, r4 = b4.y, r5 = b4.z;
        float a = 0.f;
#pragma unroll
        for (int j = 0; j < 6; ++j) {
            float s = r0 * ssw[0 * 6 + j] + r1 * ssw[1 * 6 + j] + r2 * ssw[2 * 6 + j] +
                      r3 * ssw[3 * 6 + j] + r4 * ssw[4 * 6 + j] + r5 * ssw[5 * 6 + j];
            a += sap[j] * tanh_(s);
        }
        att[k] = a;
        mx = fmaxf(mx, a);
    }
#pragma unroll
    for (int off = 32; off; off >>= 1) mx = fmaxf(mx, __shfl_xor(mx, off));
    float e[8];
    float sum = 0.f;
#pragma unroll
    for (int k = 0; k < 8; ++k) { e[k] = exp2_(L2E * (att[k] - mx)); sum += e[k]; }
#pragma unroll
    for (int off = 32; off; off >>= 1) sum += __shfl_xor(sum, off);

    float acc[6] = {0.f, 0.f, 0.f, 0.f, 0.f, 0.f};
#pragma unroll
    for (int k = 0; k < 8; ++k) {
        int l = lane + 64 * k;
        float4 f4 = *(const float4*)(F + l * 4);
        float4 b4 = *(const float4*)(Bw + l * 4);
        acc[0] += e[k] * f4.x; acc[1] += e[k] * f4.y; acc[2] += e[k] * f4.z;
        acc[3] += e[k] * b4.x; acc[4] += e[k] * b4.y; acc[5] += e[k] * b4.z;
    }
#pragma unroll
    for (int j = 0; j < 6; ++j) {
#pragma unroll
        for (int off = 32; off; off >>= 1) acc[j] += __shfl_xor(acc[j], off);
    }
    if (lane == 0) {
#pragma unroll
        for (int j = 0; j < 6; ++j) wd_atten[b * 6 + j] = acc[j] / sum;
    }
}

// ---------------------------------------------------------------------------
// 7. tail
// ---------------------------------------------------------------------------
__global__ void k_tail(const float* __restrict__ out1, const float* __restrict__ wd_atten,
                       const float* __restrict__ pg, const float* __restrict__ pb,
                       const float* __restrict__ pw, const float* __restrict__ pbias,
                       const float* __restrict__ f1w, const float* __restrict__ f1b,
                       const float* __restrict__ fg, const float* __restrict__ fb,
                       const float* __restrict__ f2w, const float* __restrict__ f2b,
                       float* __restrict__ out)
{
    int b = blockIdx.x;
    int lane = threadIdx.x;
    __shared__ float sph[6], scomb[9], sh[128], sl[6], se[6];
    const float BN = 0.9999950000374997f; // 1/sqrt(1+1e-5)

    if (lane < 6) {
        const float* posf = out1 + (size_t)((2 * BB) + b) * LL * 4 + 511 * 4;   // pos fwd, l=511
        const float* posb = out1 + (size_t)((3 * BB) + b) * LL * 4 + 511 * 4;   // pos bwd, l=511
        float v = lane < 3 ? posf[lane] : posb[lane - 3];
        float x = v * BN * pg[lane] + pb[lane];
        sph[lane] = fmaxf(x, 0.f);
        scomb[lane] = wd_atten[b * 6 + lane];
    }
    __syncthreads();
    if (lane == 0) {
        float a[3];
#pragma unroll
        for (int j = 0; j < 3; ++j) {
            float t = pbias[j];
#pragma unroll
            for (int i = 0; i < 6; ++i) t += sph[i] * pw[j * 6 + i];
            a[j] = t;
        }
        float m = fmaxf(a[0], fmaxf(a[1], a[2]));
        float e0 = exp2_(L2E * (a[0] - m)), e1 = exp2_(L2E * (a[1] - m)), e2 = exp2_(L2E * (a[2] - m));
        float s = e0 + e1 + e2;
        float x0 = e0 / s, x1 = e1 / s, x2 = e2 / s;
        scomb[6] = x0; scomb[7] = x1; scomb[8] = x2;
        out[BB * 6 + b * 3 + 0] = x0;
        out[BB * 6 + b * 3 + 1] = x1;
        out[BB * 6 + b * 3 + 2] = x2;
    }
    __syncthreads();
    for (int o = lane; o < 128; o += 64) {
        float t = f1b[o];
#pragma unroll
        for (int k = 0; k < 9; ++k) t += scomb[k] * f1w[o * 9 + k];
        float x = t * BN * fg[o] + fb[o];
        sh[o] = fmaxf(x, 0.f);
    }
    __syncthreads();
    if (lane < 6) {
        float t = f2b[lane];
        for (int k = 0; k < 128; ++k) t += sh[k] * f2w[lane * 128 + k];
        sl[lane] = t;
    }
    __syncthreads();
    if (lane < 6) {
        float m = sl[0];
#pragma unroll
        for (int j = 1; j < 6; ++j) m = fmaxf(m, sl[j]);
        se[lane] = exp2_(L2E * (sl[lane] - m));
    }
    __syncthreads();
    if (lane < 6) {
        float s = se[0] + se[1] + se[2] + se[3] + se[4] + se[5];
        out[b * 6 + lane] = se[lane] / s;
    }
}

// ---------------------------------------------------------------------------
extern "C" void kernel_launch(void* const* d_in, const int* in_sizes, int n_in,
                              void* d_out, int out_size, void* d_ws, size_t ws_size,
                              hipStream_t stream)
{
    const int* wd  = (const int*)d_in[0];
    const int* pos = (const int*)d_in[1];
    const float* wd_emb  = (const float*)d_in[2];
    const float* pos_emb = (const float*)d_in[3];
    const float* cw2 = (const float*)d_in[4];  const float* cb2 = (const float*)d_in[5];
    const float* cw3 = (const float*)d_in[6];  const float* cb3 = (const float*)d_in[7];
    const float* cw4 = (const float*)d_in[8];  const float* cb4 = (const float*)d_in[9];
    const float* wd_wih0 = (const float*)d_in[10]; const float* wd_whh0 = (const float*)d_in[11];
    const float* wd_bih0 = (const float*)d_in[12]; const float* wd_bhh0 = (const float*)d_in[13];
    const float* wd_wih1 = (const float*)d_in[14]; const float* wd_whh1 = (const float*)d_in[15];
    const float* wd_bih1 = (const float*)d_in[16]; const float* wd_bhh1 = (const float*)d_in[17];
    const float* pos_wih0 = (const float*)d_in[18]; const float* pos_whh0 = (const float*)d_in[19];
    const float* pos_bih0 = (const float*)d_in[20]; const float* pos_bhh0 = (const float*)d_in[21];
    const float* pos_wih1 = (const float*)d_in[22]; const float* pos_whh1 = (const float*)d_in[23];
    const float* pos_bih1 = (const float*)d_in[24]; const float* pos_bhh1 = (const float*)d_in[25];
    const float* squish_w   = (const float*)d_in[26];
    const float* atten_proj = (const float*)d_in[27];
    const float* posfc_gamma = (const float*)d_in[28]; const float* posfc_beta = (const float*)d_in[29];
    const float* posfc_w = (const float*)d_in[30]; const float* posfc_b = (const float*)d_in[31];
    const float* fc1_w = (const float*)d_in[32]; const float* fc1_b = (const float*)d_in[33];
    const float* fc_gamma = (const float*)d_in[34]; const float* fc_beta = (const float*)d_in[35];
    const float* fc2_w = (const float*)d_in[36]; const float* fc2_b = (const float*)d_in[37];

    float* ws = (float*)d_ws;
    size_t off = 0;
    float* P = ws + off;      off += (size_t)VV * 72 + 8;        // 1,710,512
    float* gx = ws + off;     off += (size_t)4 * BB * LL * 9;    // 9,437,184
    float* outR = ws + off;   off += (size_t)4 * BB * LL * 4;    // 4,194,304 (out0 == out1)
    float* Etab = ws + off;   off += 7200;
    float* beff = ws + off;   off += 32;
    float* Gp = ws + off;     off += PP * 18 + 14;
    float* wih1t = ws + off;  off += 216;
    float* bih1t = ws + off;  off += 40;
    float* wdat = ws + off;   off += BB * 6;

    k_build_tables<<<(8496 + 255) / 256, 256, 0, stream>>>(
        wd_wih0, wd_bih0, wd_bhh0, cw2, cb2, cw3, cb3, cw4, cb4,
        pos_emb, pos_wih0, pos_bih0, pos_bhh0,
        wd_wih1, wd_bih1, wd_bhh1, pos_wih1, pos_bih1, pos_bhh1,
        Etab, beff, Gp, wih1t, bih1t);
    k_build_P<<<1024, 256, 0, stream>>>(wd_emb, Etab, P);
    k_gather<<<(2 * BB * LL + 255) / 256, 256, 0, stream>>>(wd, pos, P, beff, Gp, gx);
    k_scan<<<128, 64, 0, stream>>>(gx, outR, wd_whh0, wd_bhh0, pos_whh0, pos_bhh0);
    k_gx1<<<(2 * BB * LL + 255) / 256, 256, 0, stream>>>(outR, wih1t, bih1t, gx);
    k_scan<<<128, 64, 0, stream>>>(gx, outR, wd_whh1, wd_bhh1, pos_whh1, pos_bhh1);
    k_atten<<<BB, 64, 0, stream>>>(outR, squish_w, atten_proj, wdat);
    k_tail<<<BB, 64, 0, stream>>>(outR, wdat, posfc_gamma, posfc_beta, posfc_w, posfc_b,
                                  fc1_w, fc1_b, fc_gamma, fc_beta, fc2_w, fc2_b, (float*)d_out);
}

// Round 5
// 158.838 us; speedup vs baseline: 3.2938x; 1.3146x over previous
//
#include <hip/hip_runtime.h>
#include <math.h>

#define BB 512   // batch
#define LL 512   // seq len
#define VV 23757 // wd vocab
#define PP 57    // pos vocab

#define L2E  1.4426950408889634f
#define NL2E (-1.4426950408889634f)
#define TL2E 2.8853900817779268f   // 2*log2(e)

__device__ __forceinline__ float rcp_(float x) { return __builtin_amdgcn_rcpf(x); }
__device__ __forceinline__ float exp2_(float x) { return __builtin_amdgcn_exp2f(x); }
__device__ __forceinline__ float tanh_(float x) { return 1.f - 2.f * rcp_(exp2_(TL2E * x) + 1.f); }

// gate scale: r,z -> -log2e ; n -> 2*log2e   (dg = dir*9 + g*3 + j)
__device__ __forceinline__ float gscale(int dg) {
    int g = (dg % 9) / 3;
    return g == 2 ? TL2E : NL2E;
}
__device__ __forceinline__ int is_rz(int dg) { return ((dg % 9) / 3) < 2; }

// quad_perm broadcast of lane K (0..2) within each 4-lane group, via DPP.
template <int K>
__device__ __forceinline__ float qb(float x) {
    constexpr int ctrl = K * 0x55;
    return __int_as_float(__builtin_amdgcn_update_dpp(0, __float_as_int(x), ctrl, 0xF, 0xF, true));
}

struct F3 { float r, z, n; };

// ---------------------------------------------------------------------------
// 1. Tables (prescaled for exp2-form gates).
// ---------------------------------------------------------------------------
__global__ void k_build_tables(const float* __restrict__ wd_wih0, const float* __restrict__ wd_bih0,
                               const float* __restrict__ wd_bhh0,
                               const float* __restrict__ cw2, const float* __restrict__ cb2,
                               const float* __restrict__ cw3, const float* __restrict__ cb3,
                               const float* __restrict__ cw4, const float* __restrict__ cb4,
                               const float* __restrict__ pos_emb,
                               const float* __restrict__ pos_wih0, const float* __restrict__ pos_bih0,
                               const float* __restrict__ pos_bhh0,
                               const float* __restrict__ wd_wih1, const float* __restrict__ wd_bih1,
                               const float* __restrict__ wd_bhh1,
                               const float* __restrict__ pos_wih1, const float* __restrict__ pos_bih1,
                               const float* __restrict__ pos_bhh1,
                               float* __restrict__ E, float* __restrict__ beff, float* __restrict__ Gp,
                               float* __restrict__ wih1t, float* __restrict__ bih1t)
{
    int idx = blockIdx.x * blockDim.x + threadIdx.x;
    if (idx < 7200) {
        int d  = idx % 100;
        int tt = (idx / 100) % 4;
        int dg = idx / 400;
        const float* wih = wd_wih0 + dg * 144;
        float acc = 0.f;
        if (tt == 0) {        // offset -2
            for (int o = 0; o < 48; ++o) acc += wih[96 + o] * cw4[o * 400 + d * 4 + 0];
        } else if (tt == 1) { // offset -1
            for (int o = 0; o < 48; ++o) acc += wih[o]      * cw2[o * 200 + d * 2 + 0];
            for (int o = 0; o < 48; ++o) acc += wih[48 + o] * cw3[o * 300 + d * 3 + 0];
            for (int o = 0; o < 48; ++o) acc += wih[96 + o] * cw4[o * 400 + d * 4 + 1];
        } else if (tt == 2) { // offset 0
            for (int o = 0; o < 48; ++o) acc += wih[o]      * cw2[o * 200 + d * 2 + 1];
            for (int o = 0; o < 48; ++o) acc += wih[48 + o] * cw3[o * 300 + d * 3 + 1];
            for (int o = 0; o < 48; ++o) acc += wih[96 + o] * cw4[o * 400 + d * 4 + 2];
        } else {              // offset +1
            for (int o = 0; o < 48; ++o) acc += wih[48 + o] * cw3[o * 300 + d * 3 + 2];
            for (int o = 0; o < 48; ++o) acc += wih[96 + o] * cw4[o * 400 + d * 4 + 3];
        }
        E[idx] = acc;
    } else if (idx < 7218) {
        int dg = idx - 7200;
        float acc = wd_bih0[dg];
        for (int o = 0; o < 48; ++o) acc += wd_wih0[dg * 144 + o]      * cb2[o];
        for (int o = 0; o < 48; ++o) acc += wd_wih0[dg * 144 + 48 + o] * cb3[o];
        for (int o = 0; o < 48; ++o) acc += wd_wih0[dg * 144 + 96 + o] * cb4[o];
        if (is_rz(dg)) acc += wd_bhh0[dg];
        beff[dg] = gscale(dg) * acc;
    } else if (idx < 8244) {
        int k = idx - 7218;
        int dg = k % 18;
        int p  = k / 18;
        float acc = pos_bih0[dg];
        for (int d = 0; d < 100; ++d) acc += pos_emb[p * 100 + d] * pos_wih0[dg * 100 + d];
        if (is_rz(dg)) acc += pos_bhh0[dg];
        Gp[p * 18 + dg] = gscale(dg) * acc;
    } else if (idx < 8352) {
        int i = idx - 8244; int dg = i / 6;
        wih1t[i] = gscale(dg) * wd_wih1[i];
    } else if (idx < 8370) {
        int dg = idx - 8352;
        float a = wd_bih1[dg] + (is_rz(dg) ? wd_bhh1[dg] : 0.f);
        bih1t[dg] = gscale(dg) * a;
    } else if (idx < 8478) {
        int i = idx - 8370; int dg = i / 6;
        wih1t[108 + i] = gscale(dg) * pos_wih1[i];
    } else if (idx < 8496) {
        int dg = idx - 8478;
        float a = pos_bih1[dg] + (is_rz(dg) ? pos_bhh1[dg] : 0.f);
        bih1t[18 + dg] = gscale(dg) * a;
    }
}

// ---------------------------------------------------------------------------
// 2. P~[v][tap][dg] = s_g * (wd_emb[v,:] . E[dg][tap][:])
// ---------------------------------------------------------------------------
__global__ void k_build_P(const float* __restrict__ wd_emb, const float* __restrict__ E,
                          float* __restrict__ P)
{
    __shared__ float sE[7200];
    for (int i = threadIdx.x; i < 7200; i += blockDim.x) sE[i] = E[i];
    __syncthreads();
    const long total = (long)VV * 72;
    for (long idx = (long)blockIdx.x * blockDim.x + threadIdx.x; idx < total;
         idx += (long)gridDim.x * blockDim.x) {
        int r = (int)(idx % 72);
        long v = idx / 72;
        int dg = r % 18;
        int tt = r / 18;
        const float* emb = wd_emb + v * 100;
        const float* e = sE + dg * 400 + tt * 100;
        float acc = 0.f;
#pragma unroll
        for (int d = 0; d < 100; ++d) acc += emb[d] * e[d];
        P[idx] = gscale(dg) * acc;
    }
}

// ---------------------------------------------------------------------------
// 3. Gather: one thread per (branch,b,l), all 18 gates, prescaled already.
//    gx layout: [(branch*2+dir)*BB + b][l][j][g]  (9 floats / (chain,l))
// ---------------------------------------------------------------------------
__global__ void k_gather(const int* __restrict__ wd, const int* __restrict__ pos,
                         const float* __restrict__ P, const float* __restrict__ beff,
                         const float* __restrict__ Gp, float* __restrict__ gx)
{
    int idx = blockIdx.x * blockDim.x + threadIdx.x;
    if (idx >= 2 * BB * LL) return;
    int branch = idx >= BB * LL;
    int k = idx - branch * BB * LL;
    int l = k % LL, b = k / LL;

    float v[18];
    if (!branch) {
#pragma unroll
        for (int i = 0; i < 18; ++i) v[i] = beff[i];
        const int* row = wd + b * LL;
#pragma unroll
        for (int t = 0; t < 4; ++t) {
            int ll = l - 2 + t;
            if (ll >= 0 && ll < LL) {
                const float* p = P + (long)row[ll] * 72 + t * 18;
#pragma unroll
                for (int i = 0; i < 18; ++i) v[i] += p[i];
            }
        }
    } else {
        const float* p = Gp + pos[k] * 18;
#pragma unroll
        for (int i = 0; i < 18; ++i) v[i] = p[i];
    }
    long base0 = ((long)(branch * 2 + 0) * BB + b) * (LL * 9) + l * 9;
    long base1 = ((long)(branch * 2 + 1) * BB + b) * (LL * 9) + l * 9;
#pragma unroll
    for (int j = 0; j < 3; ++j)
#pragma unroll
        for (int g = 0; g < 3; ++g) {
            gx[base0 + j * 3 + g] = v[g * 3 + j];
            gx[base1 + j * 3 + g] = v[9 + g * 3 + j];
        }
}

// ---------------------------------------------------------------------------
// 4. Chunked GRU scan. Block = 1 chain x 16 chunks x 4 lanes (64 threads).
//    Chunk c: t = 32c - 64 + i, i in [0,96); h forced 0 while t<0; stores
//    only for i in [64,96) (the 32 "real" steps). Warm-up error <= ~0.8^64.
//    gx layout: [chain][l][j][3]; out layout: [chain][l][4].
// ---------------------------------------------------------------------------
__global__ void __launch_bounds__(64) k_scan(
        const float* __restrict__ gx0, float* __restrict__ out,
        const float* __restrict__ whhA, const float* __restrict__ bhhA,
        const float* __restrict__ whhB, const float* __restrict__ bhhB)
{
    __shared__ float lbuf[16 * 81];
    int lane = threadIdx.x;
    int c = lane >> 2, sub = lane & 3;     // c = chunk
    int jj = sub < 3 ? sub : 2;
    int chain = blockIdx.x;                // 0..2047
    int branch = chain >> 10;
    int rem = chain & 1023;
    int dir = rem >> 9;

    const float* whh = (branch ? whhB : whhA) + dir * 27;
    const float* bhh = (branch ? bhhB : bhhA) + dir * 9;

    float wr0 = NL2E * whh[jj * 3 + 0], wr1 = NL2E * whh[jj * 3 + 1], wr2 = NL2E * whh[jj * 3 + 2];
    float wz0 = NL2E * whh[(3 + jj) * 3 + 0], wz1 = NL2E * whh[(3 + jj) * 3 + 1], wz2 = NL2E * whh[(3 + jj) * 3 + 2];
    float wn0 = TL2E * whh[(6 + jj) * 3 + 0], wn1 = TL2E * whh[(6 + jj) * 3 + 1], wn2 = TL2E * whh[(6 + jj) * 3 + 2];
    float bnx = TL2E * bhh[6 + jj];

    // byte offset of scan-step t (t=0 is l=0 fwd / l=511 bwd)
    int rowbase = chain * (LL * 36);
    int start = rowbase + jj * 12 + (dir ? 511 * 36 : 0);
    int sstp = dir ? -36 : 36;

    int t0 = c * 32 - 64;
    const char* gxc = (const char*)gx0;
    F3 buf[16];
#pragma unroll
    for (int s = 0; s < 16; ++s) {
        int tt = t0 + s; tt = tt < 0 ? 0 : tt;
        buf[s] = *(const F3*)(gxc + start + tt * sstp);
    }
    int pft = t0 + 16;

    char* ob = (char*)out + (size_t)chain * (LL * 16) + sub * 64;

    float h = 0.f;
    for (int g = 0; g < 6; ++g) {
#pragma unroll
        for (int s = 0; s < 16; ++s) {
            int t = t0 + g * 16 + s;
            F3 gv = buf[s];
            int tt = pft < 0 ? 0 : (pft > LL - 1 ? LL - 1 : pft);
            buf[s] = *(const F3*)(gxc + start + tt * sstp);
            ++pft;

            float h0 = qb<0>(h), h1 = qb<1>(h), h2 = qb<2>(h);
            float hm1 = h - 1.f;
            float sr = fmaf(wr0, h0, gv.r) + fmaf(wr1, h1, wr2 * h2);
            float sz = fmaf(wz0, h0, gv.z) + fmaf(wz1, h1, wz2 * h2);
            float gn3 = fmaf(wn0, h0, fmaf(wn1, h1, fmaf(wn2, h2, bnx)));
            float r = rcp_(1.f + exp2_(sr));
            float z = rcp_(1.f + exp2_(sz));
            float y2 = fmaf(r, gn3, gv.n);
            float u = rcp_(1.f + exp2_(y2));
            float a = fmaf(2.f, u, hm1);
            float n = fmaf(-2.f, u, 1.f);
            float hn = fmaf(z, a, n);
            h = (t >= 0) ? hn : 0.f;
            lbuf[s * 81 + c * 5 + sub] = h;
        }
        __syncthreads();
        if (g >= 4) {
            int tbase = t0 + g * 16;
            int l0 = dir ? (LL - 1 - tbase - 15) : tbase;
#pragma unroll
            for (int i = 0; i < 4; ++i) {
                int lofs = sub * 4 + i;
                int s = dir ? (15 - lofs) : lofs;
                float4 vv;
                vv.x = lbuf[s * 81 + c * 5 + 0];
                vv.y = lbuf[s * 81 + c * 5 + 1];
                vv.z = lbuf[s * 81 + c * 5 + 2];
                vv.w = lbuf[s * 81 + c * 5 + 3];
                *(float4*)(ob + (size_t)l0 * 16 + i * 16) = vv;
            }
        }
        __syncthreads();
    }
}

// ---------------------------------------------------------------------------
// 5. layer-1 gx: one thread per (branch,b,l); all 18 gates, prescaled tables.
// ---------------------------------------------------------------------------
__global__ void k_gx1(const float* __restrict__ out0,
                      const float* __restrict__ wih1t, const float* __restrict__ bih1t,
                      float* __restrict__ gx)
{
    int idx = blockIdx.x * blockDim.x + threadIdx.x;
    if (idx >= 2 * BB * LL) return;
    int branch = idx >= BB * LL;
    int k = idx - branch * BB * LL;
    int l = k % LL, b = k / LL;

    const float4 f4 = *(const float4*)(out0 + ((size_t)((branch * 2 + 0) * BB + b) * LL + l) * 4);
    const float4 b4 = *(const float4*)(out0 + ((size_t)((branch * 2 + 1) * BB + b) * LL + l) * 4);
    float row[6] = {f4.x, f4.y, f4.z, b4.x, b4.y, b4.z};
    const float* W = wih1t + branch * 108;
    const float* Bv = bih1t + branch * 18;

    float v[18];
#pragma unroll
    for (int dg = 0; dg < 18; ++dg) {
        float acc = Bv[dg];
#pragma unroll
        for (int cix = 0; cix < 6; ++cix) acc += row[cix] * W[dg * 6 + cix];
        v[dg] = acc;
    }
    long base0 = ((long)(branch * 2 + 0) * BB + b) * (LL * 9) + l * 9;
    long base1 = ((long)(branch * 2 + 1) * BB + b) * (LL * 9) + l * 9;
#pragma unroll
    for (int j = 0; j < 3; ++j)
#pragma unroll
        for (int g = 0; g < 3; ++g) {
            gx[base0 + j * 3 + g] = v[g * 3 + j];
            gx[base1 + j * 3 + g] = v[9 + g * 3 + j];
        }
}

// ---------------------------------------------------------------------------
// 6. Fused head: attention over wd_out + posfc/auxi + fc1/fc2 softmax.
// ---------------------------------------------------------------------------
__global__ void k_head(const float* __restrict__ out1,
                       const float* __restrict__ sw, const float* __restrict__ ap,
                       const float* __restrict__ pg, const float* __restrict__ pb,
                       const float* __restrict__ pw, const float* __restrict__ pbias,
                       const float* __restrict__ f1w, const float* __restrict__ f1b,
                       const float* __restrict__ fg, const float* __restrict__ fb,
                       const float* __restrict__ f2w, const float* __restrict__ f2b,
                       float* __restrict__ out)
{
    int b = blockIdx.x;
    int lane = threadIdx.x;
    __shared__ float ssw[36], sap[6], sph[6], scomb[9], sh[128], sl[6], se[6];
    const float BN = 0.9999950000374997f; // 1/sqrt(1+1e-5)

    if (lane < 36) ssw[lane] = sw[lane];
    if (lane < 6) {
        sap[lane] = ap[lane];
        const float* posf = out1 + (size_t)((2 * BB) + b) * LL * 4 + 511 * 4;
        const float* posb = out1 + (size_t)((3 * BB) + b) * LL * 4 + 511 * 4;
        float v = lane < 3 ? posf[lane] : posb[lane - 3];
        float x = v * BN * pg[lane] + pb[lane];
        sph[lane] = fmaxf(x, 0.f);
    }
    __syncthreads();

    const float* F = out1 + (size_t)b * LL * 4;
    const float* Bw = out1 + (size_t)(BB + b) * LL * 4;

    float att[8];
    float mx = -1e30f;
#pragma unroll
    for (int k = 0; k < 8; ++k) {
        int l = lane + 64 * k;
        float4 f4 = *(const float4*)(F + l * 4);
        float4 b4 = *(const float4*)(Bw + l * 4);
        float r0 = f4.x, r1 = f4.y, r2 = f4.z, r3 = b4.x, r4 = b4.y, r5 = b4.z;
        float a = 0.f;
#pragma unroll
        for (int j = 0; j < 6; ++j) {
            float s = r0 * ssw[0 * 6 + j] + r1 * ssw[1 * 6 + j] + r2 * ssw[2 * 6 + j] +
                      r3 * ssw[3 * 6 + j] + r4 * ssw[4 * 6 + j] + r5 * ssw[5 * 6 + j];
            a += sap[j] * tanh_(s);
        }
        att[k] = a;
        mx = fmaxf(mx, a);
    }
#pragma unroll
    for (int off = 32; off; off >>= 1) mx = fmaxf(mx, __shfl_xor(mx, off));
    float e[8];
    float sum = 0.f;
#pragma unroll
    for (int k = 0; k < 8; ++k) { e[k] = exp2_(L2E * (att[k] - mx)); sum += e[k]; }
#pragma unroll
    for (int off = 32; off; off >>= 1) sum += __shfl_xor(sum, off);

    float acc[6] = {0.f, 0.f, 0.f, 0.f, 0.f, 0.f};
#pragma unroll
    for (int k = 0; k < 8; ++k) {
        int l = lane + 64 * k;
        float4 f4 = *(const float4*)(F + l * 4);
        float4 b4 = *(const float4*)(Bw + l * 4);
        acc[0] += e[k] * f4.x; acc[1] += e[k] * f4.y; acc[2] += e[k] * f4.z;
        acc[3] += e[k] * b4.x; acc[4] += e[k] * b4.y; acc[5] += e[k] * b4.z;
    }
#pragma unroll
    for (int j = 0; j < 6; ++j) {
#pragma unroll
        for (int off = 32; off; off >>= 1) acc[j] += __shfl_xor(acc[j], off);
    }
    if (lane < 6) scomb[lane] = acc[lane] / sum;
    __syncthreads();

    if (lane == 0) {
        float a[3];
#pragma unroll
        for (int j = 0; j < 3; ++j) {
            float t = pbias[j];
#pragma unroll
            for (int i = 0; i < 6; ++i) t += sph[i] * pw[j * 6 + i];
            a[j] = t;
        }
        float m = fmaxf(a[0], fmaxf(a[1], a[2]));
        float e0 = exp2_(L2E * (a[0] - m)), e1 = exp2_(L2E * (a[1] - m)), e2 = exp2_(L2E * (a[2] - m));
        float s = e0 + e1 + e2;
        float x0 = e0 / s, x1 = e1 / s, x2 = e2 / s;
        scomb[6] = x0; scomb[7] = x1; scomb[8] = x2;
        out[BB * 6 + b * 3 + 0] = x0;
        out[BB * 6 + b * 3 + 1] = x1;
        out[BB * 6 + b * 3 + 2] = x2;
    }
    __syncthreads();
    for (int o = lane; o < 128; o += 64) {
        float t = f1b[o];
#pragma unroll
        for (int k = 0; k < 9; ++k) t += scomb[k] * f1w[o * 9 + k];
        float x = t * BN * fg[o] + fb[o];
        sh[o] = fmaxf(x, 0.f);
    }
    __syncthreads();
    if (lane < 6) {
        float t = f2b[lane];
        for (int k = 0; k < 128; ++k) t += sh[k] * f2w[lane * 128 + k];
        sl[lane] = t;
    }
    __syncthreads();
    if (lane < 6) {
        float m = sl[0];
#pragma unroll
        for (int j = 1; j < 6; ++j) m = fmaxf(m, sl[j]);
        se[lane] = exp2_(L2E * (sl[lane] - m));
    }
    __syncthreads();
    if (lane < 6) {
        float s = se[0] + se[1] + se[2] + se[3] + se[4] + se[5];
        out[b * 6 + lane] = se[lane] / s;
    }
}

// ---------------------------------------------------------------------------
extern "C" void kernel_launch(void* const* d_in, const int* in_sizes, int n_in,
                              void* d_out, int out_size, void* d_ws, size_t ws_size,
                              hipStream_t stream)
{
    const int* wd  = (const int*)d_in[0];
    const int* pos = (const int*)d_in[1];
    const float* wd_emb  = (const float*)d_in[2];
    const float* pos_emb = (const float*)d_in[3];
    const float* cw2 = (const float*)d_in[4];  const float* cb2 = (const float*)d_in[5];
    const float* cw3 = (const float*)d_in[6];  const float* cb3 = (const float*)d_in[7];
    const float* cw4 = (const float*)d_in[8];  const float* cb4 = (const float*)d_in[9];
    const float* wd_wih0 = (const float*)d_in[10]; const float* wd_whh0 = (const float*)d_in[11];
    const float* wd_bih0 = (const float*)d_in[12]; const float* wd_bhh0 = (const float*)d_in[13];
    const float* wd_wih1 = (const float*)d_in[14]; const float* wd_whh1 = (const float*)d_in[15];
    const float* wd_bih1 = (const float*)d_in[16]; const float* wd_bhh1 = (const float*)d_in[17];
    const float* pos_wih0 = (const float*)d_in[18]; const float* pos_whh0 = (const float*)d_in[19];
    const float* pos_bih0 = (const float*)d_in[20]; const float* pos_bhh0 = (const float*)d_in[21];
    const float* pos_wih1 = (const float*)d_in[22]; const float* pos_whh1 = (const float*)d_in[23];
    const float* pos_bih1 = (const float*)d_in[24]; const float* pos_bhh1 = (const float*)d_in[25];
    const float* squish_w   = (const float*)d_in[26];
    const float* atten_proj = (const float*)d_in[27];
    const float* posfc_gamma = (const float*)d_in[28]; const float* posfc_beta = (const float*)d_in[29];
    const float* posfc_w = (const float*)d_in[30]; const float* posfc_b = (const float*)d_in[31];
    const float* fc1_w = (const float*)d_in[32]; const float* fc1_b = (const float*)d_in[33];
    const float* fc_gamma = (const float*)d_in[34]; const float* fc_beta = (const float*)d_in[35];
    const float* fc2_w = (const float*)d_in[36]; const float* fc2_b = (const float*)d_in[37];

    float* ws = (float*)d_ws;
    size_t off = 0;
    float* P = ws + off;      off += (size_t)VV * 72 + 8;        // 1,710,512
    float* gx = ws + off;     off += (size_t)4 * BB * LL * 9;    // 9,437,184
    float* outR = ws + off;   off += (size_t)4 * BB * LL * 4;    // 4,194,304
    float* Etab = ws + off;   off += 7200;
    float* beff = ws + off;   off += 32;
    float* Gp = ws + off;     off += PP * 18 + 14;
    float* wih1t = ws + off;  off += 216;
    float* bih1t = ws + off;  off += 40;

    k_build_tables<<<(8496 + 255) / 256, 256, 0, stream>>>(
        wd_wih0, wd_bih0, wd_bhh0, cw2, cb2, cw3, cb3, cw4, cb4,
        pos_emb, pos_wih0, pos_bih0, pos_bhh0,
        wd_wih1, wd_bih1, wd_bhh1, pos_wih1, pos_bih1, pos_bhh1,
        Etab, beff, Gp, wih1t, bih1t);
    k_build_P<<<1024, 256, 0, stream>>>(wd_emb, Etab, P);
    k_gather<<<(2 * BB * LL + 255) / 256, 256, 0, stream>>>(wd, pos, P, beff, Gp, gx);
    k_scan<<<2048, 64, 0, stream>>>(gx, outR, wd_whh0, wd_bhh0, pos_whh0, pos_bhh0);
    k_gx1<<<(2 * BB * LL + 255) / 256, 256, 0, stream>>>(outR, wih1t, bih1t, gx);
    k_scan<<<2048, 64, 0, stream>>>(gx, outR, wd_whh1, wd_bhh1, pos_whh1, pos_bhh1);
    k_head<<<BB, 64, 0, stream>>>(outR, squish_w, atten_proj, posfc_gamma, posfc_beta,
                                  posfc_w, posfc_b, fc1_w, fc1_b, fc_gamma, fc_beta,
                                  fc2_w, fc2_b, (float*)d_out);
}

// Round 6
// 126.547 us; speedup vs baseline: 4.1343x; 1.2552x over previous
//
#include <hip/hip_runtime.h>
#include <math.h>

#define BB 512   // batch
#define LL 512   // seq len
#define VV 23757 // wd vocab
#define PP 57    // pos vocab

#define L2E  1.4426950408889634f
#define NL2E (-1.4426950408889634f)
#define TL2E 2.8853900817779268f   // 2*log2(e)

__device__ __forceinline__ float rcp_(float x) { return __builtin_amdgcn_rcpf(x); }
__device__ __forceinline__ float exp2_(float x) { return __builtin_amdgcn_exp2f(x); }
__device__ __forceinline__ float tanh_(float x) { return 1.f - 2.f * rcp_(exp2_(TL2E * x) + 1.f); }

// gate scale: r,z -> -log2e ; n -> 2*log2e   (dg = dir*9 + g*3 + j)
__device__ __forceinline__ float gscale(int dg) {
    int g = (dg % 9) / 3;
    return g == 2 ? TL2E : NL2E;
}
__device__ __forceinline__ int is_rz(int dg) { return ((dg % 9) / 3) < 2; }

// quad_perm broadcast of lane K (0..2) within each 4-lane group, via DPP.
template <int K>
__device__ __forceinline__ float qb(float x) {
    constexpr int ctrl = K * 0x55;
    return __int_as_float(__builtin_amdgcn_update_dpp(0, __float_as_int(x), ctrl, 0xF, 0xF, true));
}

struct F3 { float r, z, n; };

// ---------------------------------------------------------------------------
// 1. Tables (prescaled for exp2-form gates). E kept raw; scale applied in
//    k_build_P.  Layouts as before.
// ---------------------------------------------------------------------------
__global__ void k_build_tables(const float* __restrict__ wd_wih0, const float* __restrict__ wd_bih0,
                               const float* __restrict__ wd_bhh0,
                               const float* __restrict__ cw2, const float* __restrict__ cb2,
                               const float* __restrict__ cw3, const float* __restrict__ cb3,
                               const float* __restrict__ cw4, const float* __restrict__ cb4,
                               const float* __restrict__ pos_emb,
                               const float* __restrict__ pos_wih0, const float* __restrict__ pos_bih0,
                               const float* __restrict__ pos_bhh0,
                               const float* __restrict__ wd_wih1, const float* __restrict__ wd_bih1,
                               const float* __restrict__ wd_bhh1,
                               const float* __restrict__ pos_wih1, const float* __restrict__ pos_bih1,
                               const float* __restrict__ pos_bhh1,
                               float* __restrict__ E, float* __restrict__ beff, float* __restrict__ Gp,
                               float* __restrict__ wih1t, float* __restrict__ bih1t)
{
    int idx = blockIdx.x * blockDim.x + threadIdx.x;
    if (idx < 7200) {
        int d  = idx % 100;
        int tt = (idx / 100) % 4;
        int dg = idx / 400;
        const float* wih = wd_wih0 + dg * 144;
        float acc = 0.f;
        if (tt == 0) {        // offset -2
            for (int o = 0; o < 48; ++o) acc += wih[96 + o] * cw4[o * 400 + d * 4 + 0];
        } else if (tt == 1) { // offset -1
            for (int o = 0; o < 48; ++o) acc += wih[o]      * cw2[o * 200 + d * 2 + 0];
            for (int o = 0; o < 48; ++o) acc += wih[48 + o] * cw3[o * 300 + d * 3 + 0];
            for (int o = 0; o < 48; ++o) acc += wih[96 + o] * cw4[o * 400 + d * 4 + 1];
        } else if (tt == 2) { // offset 0
            for (int o = 0; o < 48; ++o) acc += wih[o]      * cw2[o * 200 + d * 2 + 1];
            for (int o = 0; o < 48; ++o) acc += wih[48 + o] * cw3[o * 300 + d * 3 + 1];
            for (int o = 0; o < 48; ++o) acc += wih[96 + o] * cw4[o * 400 + d * 4 + 2];
        } else {              // offset +1
            for (int o = 0; o < 48; ++o) acc += wih[48 + o] * cw3[o * 300 + d * 3 + 2];
            for (int o = 0; o < 48; ++o) acc += wih[96 + o] * cw4[o * 400 + d * 4 + 3];
        }
        E[idx] = acc;
    } else if (idx < 7218) {
        int dg = idx - 7200;
        float acc = wd_bih0[dg];
        for (int o = 0; o < 48; ++o) acc += wd_wih0[dg * 144 + o]      * cb2[o];
        for (int o = 0; o < 48; ++o) acc += wd_wih0[dg * 144 + 48 + o] * cb3[o];
        for (int o = 0; o < 48; ++o) acc += wd_wih0[dg * 144 + 96 + o] * cb4[o];
        if (is_rz(dg)) acc += wd_bhh0[dg];
        beff[dg] = gscale(dg) * acc;
    } else if (idx < 8244) {
        int k = idx - 7218;
        int dg = k % 18;
        int p  = k / 18;
        float acc = pos_bih0[dg];
        for (int d = 0; d < 100; ++d) acc += pos_emb[p * 100 + d] * pos_wih0[dg * 100 + d];
        if (is_rz(dg)) acc += pos_bhh0[dg];
        Gp[p * 18 + dg] = gscale(dg) * acc;
    } else if (idx < 8352) {
        int i = idx - 8244; int dg = i / 6;
        wih1t[i] = gscale(dg) * wd_wih1[i];
    } else if (idx < 8370) {
        int dg = idx - 8352;
        float a = wd_bih1[dg] + (is_rz(dg) ? wd_bhh1[dg] : 0.f);
        bih1t[dg] = gscale(dg) * a;
    } else if (idx < 8478) {
        int i = idx - 8370; int dg = i / 6;
        wih1t[108 + i] = gscale(dg) * pos_wih1[i];
    } else if (idx < 8496) {
        int dg = idx - 8478;
        float a = pos_bih1[dg] + (is_rz(dg) ? pos_bhh1[dg] : 0.f);
        bih1t[18 + dg] = gscale(dg) * a;
    }
}

// ---------------------------------------------------------------------------
// 2. P~[v][tap][dg] = s_g * (wd_emb[v,:] . E[dg][tap][:])
//    Register-blocked: thread = 4 vocab rows x 9 outputs; E transposed in
//    LDS as [d][72] (conflict-free: og*9 mod 32 covers 8 distinct banks).
// ---------------------------------------------------------------------------
__global__ void __launch_bounds__(256) k_build_P(const float* __restrict__ wd_emb,
                                                 const float* __restrict__ E,
                                                 float* __restrict__ P)
{
    __shared__ float sEt[7200]; // [d][r], r = tt*18+dg
    for (int i = threadIdx.x; i < 7200; i += 256) {
        int d = i % 100, r = i / 100;
        int tt = r / 18, dg = r % 18;
        sEt[d * 72 + r] = E[dg * 400 + tt * 100 + d];
    }
    __syncthreads();
    int T = blockIdx.x * 256 + threadIdx.x;
    int og = T & 7;
    int vb = T >> 3;
    int v0 = vb * 4;
    if (v0 >= VV) return;
    int vlim = VV - 1 - v0;  // max usable vi
    float gs[9];
#pragma unroll
    for (int k = 0; k < 9; ++k) {
        int dg = (og * 9 + k) % 18;
        gs[k] = ((dg % 9) / 3 == 2) ? TL2E : NL2E;
    }
    float acc[4][9];
#pragma unroll
    for (int vi = 0; vi < 4; ++vi)
#pragma unroll
        for (int k = 0; k < 9; ++k) acc[vi][k] = 0.f;

    const float* e0 = wd_emb + (size_t)v0 * 100;
#pragma unroll 1
    for (int d4 = 0; d4 < 25; ++d4) {
        float4 ev[4];
#pragma unroll
        for (int vi = 0; vi < 4; ++vi) {
            int vv = vi <= vlim ? vi : vlim;
            ev[vi] = *(const float4*)(e0 + vv * 100 + d4 * 4);
        }
#pragma unroll
        for (int dd = 0; dd < 4; ++dd) {
            int d = d4 * 4 + dd;
            const float* et = sEt + d * 72 + og * 9;
            float em0 = ((const float*)&ev[0])[dd];
            float em1 = ((const float*)&ev[1])[dd];
            float em2 = ((const float*)&ev[2])[dd];
            float em3 = ((const float*)&ev[3])[dd];
#pragma unroll
            for (int k = 0; k < 9; ++k) {
                float e = et[k];
                acc[0][k] = fmaf(em0, e, acc[0][k]);
                acc[1][k] = fmaf(em1, e, acc[1][k]);
                acc[2][k] = fmaf(em2, e, acc[2][k]);
                acc[3][k] = fmaf(em3, e, acc[3][k]);
            }
        }
    }
#pragma unroll
    for (int vi = 0; vi < 4; ++vi) {
        if (vi <= vlim) {
            float* p = P + (size_t)(v0 + vi) * 72 + og * 9;
#pragma unroll
            for (int k = 0; k < 9; ++k) p[k] = gs[k] * acc[vi][k];
        }
    }
}

// ---------------------------------------------------------------------------
// 3. Gather: one thread per (branch,b,l), all 18 gates, prescaled already.
//    gx layout: [(branch*2+dir)*BB + b][l][j][g]  (9 floats / (chain,l))
// ---------------------------------------------------------------------------
__global__ void k_gather(const int* __restrict__ wd, const int* __restrict__ pos,
                         const float* __restrict__ P, const float* __restrict__ beff,
                         const float* __restrict__ Gp, float* __restrict__ gx)
{
    int idx = blockIdx.x * blockDim.x + threadIdx.x;
    if (idx >= 2 * BB * LL) return;
    int branch = idx >= BB * LL;
    int k = idx - branch * BB * LL;
    int l = k % LL, b = k / LL;

    float v[18];
    if (!branch) {
#pragma unroll
        for (int i = 0; i < 18; ++i) v[i] = beff[i];
        const int* row = wd + b * LL;
#pragma unroll
        for (int t = 0; t < 4; ++t) {
            int ll = l - 2 + t;
            if (ll >= 0 && ll < LL) {
                const float* p = P + (long)row[ll] * 72 + t * 18;
#pragma unroll
                for (int i = 0; i < 18; ++i) v[i] += p[i];
            }
        }
    } else {
        const float* p = Gp + pos[k] * 18;
#pragma unroll
        for (int i = 0; i < 18; ++i) v[i] = p[i];
    }
    long base0 = ((long)(branch * 2 + 0) * BB + b) * (LL * 9) + l * 9;
    long base1 = ((long)(branch * 2 + 1) * BB + b) * (LL * 9) + l * 9;
#pragma unroll
    for (int j = 0; j < 3; ++j)
#pragma unroll
        for (int g = 0; g < 3; ++g) {
            gx[base0 + j * 3 + g] = v[g * 3 + j];
            gx[base1 + j * 3 + g] = v[9 + g * 3 + j];
        }
}

// ---------------------------------------------------------------------------
// 4. Chunked GRU scan, layer 0 (reads gx). Block = 1 chain x 16 chunks x
//    4 lanes. Chunk c: t = 32c-64+i, i in [0,96); h forced 0 while t<0;
//    stores only i in [64,96). out layout: [chain][l][4].
// ---------------------------------------------------------------------------
__global__ void __launch_bounds__(64) k_scan(
        const float* __restrict__ gx0, float* __restrict__ out,
        const float* __restrict__ whhA, const float* __restrict__ bhhA,
        const float* __restrict__ whhB, const float* __restrict__ bhhB)
{
    __shared__ float lbuf[16 * 81];
    int lane = threadIdx.x;
    int c = lane >> 2, sub = lane & 3;     // c = chunk
    int jj = sub < 3 ? sub : 2;
    int chain = blockIdx.x;                // 0..2047
    int branch = chain >> 10;
    int rem = chain & 1023;
    int dir = rem >> 9;

    const float* whh = (branch ? whhB : whhA) + dir * 27;
    const float* bhh = (branch ? bhhB : bhhA) + dir * 9;

    float wr0 = NL2E * whh[jj * 3 + 0], wr1 = NL2E * whh[jj * 3 + 1], wr2 = NL2E * whh[jj * 3 + 2];
    float wz0 = NL2E * whh[(3 + jj) * 3 + 0], wz1 = NL2E * whh[(3 + jj) * 3 + 1], wz2 = NL2E * whh[(3 + jj) * 3 + 2];
    float wn0 = TL2E * whh[(6 + jj) * 3 + 0], wn1 = TL2E * whh[(6 + jj) * 3 + 1], wn2 = TL2E * whh[(6 + jj) * 3 + 2];
    float bnx = TL2E * bhh[6 + jj];

    int rowbase = chain * (LL * 36);
    int start = rowbase + jj * 12 + (dir ? 511 * 36 : 0);
    int sstp = dir ? -36 : 36;

    int t0 = c * 32 - 64;
    const char* gxc = (const char*)gx0;
    F3 buf[16];
#pragma unroll
    for (int s = 0; s < 16; ++s) {
        int tt = t0 + s; tt = tt < 0 ? 0 : tt;
        buf[s] = *(const F3*)(gxc + start + tt * sstp);
    }
    int pft = t0 + 16;

    char* ob = (char*)out + (size_t)chain * (LL * 16) + sub * 64;

    float h = 0.f;
    for (int g = 0; g < 6; ++g) {
#pragma unroll
        for (int s = 0; s < 16; ++s) {
            int t = t0 + g * 16 + s;
            F3 gv = buf[s];
            int tt = pft < 0 ? 0 : (pft > LL - 1 ? LL - 1 : pft);
            buf[s] = *(const F3*)(gxc + start + tt * sstp);
            ++pft;

            float h0 = qb<0>(h), h1 = qb<1>(h), h2 = qb<2>(h);
            float hm1 = h - 1.f;
            float sr = fmaf(wr0, h0, gv.r) + fmaf(wr1, h1, wr2 * h2);
            float sz = fmaf(wz0, h0, gv.z) + fmaf(wz1, h1, wz2 * h2);
            float gn3 = fmaf(wn0, h0, fmaf(wn1, h1, fmaf(wn2, h2, bnx)));
            float r = rcp_(1.f + exp2_(sr));
            float z = rcp_(1.f + exp2_(sz));
            float y2 = fmaf(r, gn3, gv.n);
            float u = rcp_(1.f + exp2_(y2));
            float a = fmaf(2.f, u, hm1);
            float n = fmaf(-2.f, u, 1.f);
            float hn = fmaf(z, a, n);
            h = (t >= 0) ? hn : 0.f;
            lbuf[s * 81 + c * 5 + sub] = h;
        }
        __syncthreads();
        if (g >= 4) {
            int tbase = t0 + g * 16;
            int l0 = dir ? (LL - 1 - tbase - 15) : tbase;
#pragma unroll
            for (int i = 0; i < 4; ++i) {
                int lofs = sub * 4 + i;
                int s = dir ? (15 - lofs) : lofs;
                float4 vv;
                vv.x = lbuf[s * 81 + c * 5 + 0];
                vv.y = lbuf[s * 81 + c * 5 + 1];
                vv.z = lbuf[s * 81 + c * 5 + 2];
                vv.w = lbuf[s * 81 + c * 5 + 3];
                *(float4*)(ob + (size_t)l0 * 16 + i * 16) = vv;
            }
        }
        __syncthreads();
    }
}

// ---------------------------------------------------------------------------
// 5. Chunked GRU scan, layer 1 with FUSED input projection (no gx buffer):
//    per step, gates computed in-register from prefetched out0 rows.
//    8-deep prefetch, 12 groups of 8 steps (64 warm-up + 32 real).
// ---------------------------------------------------------------------------
__global__ void __launch_bounds__(64) k_scan1(
        const float* __restrict__ out0, float* __restrict__ out1,
        const float* __restrict__ whhA, const float* __restrict__ bhhA,
        const float* __restrict__ whhB, const float* __restrict__ bhhB,
        const float* __restrict__ wih1t, const float* __restrict__ bih1t)
{
    __shared__ float lbuf[8 * 81];
    int lane = threadIdx.x;
    int c = lane >> 2, sub = lane & 3;
    int jj = sub < 3 ? sub : 2;
    int chain = blockIdx.x;
    int branch = chain >> 10;
    int rem = chain & 1023;
    int dir = rem >> 9;
    int b = rem & 511;

    const float* whh = (branch ? whhB : whhA) + dir * 27;
    const float* bhh = (branch ? bhhB : bhhA) + dir * 9;

    float wr0 = NL2E * whh[jj * 3 + 0], wr1 = NL2E * whh[jj * 3 + 1], wr2 = NL2E * whh[jj * 3 + 2];
    float wz0 = NL2E * whh[(3 + jj) * 3 + 0], wz1 = NL2E * whh[(3 + jj) * 3 + 1], wz2 = NL2E * whh[(3 + jj) * 3 + 2];
    float wn0 = TL2E * whh[(6 + jj) * 3 + 0], wn1 = TL2E * whh[(6 + jj) * 3 + 1], wn2 = TL2E * whh[(6 + jj) * 3 + 2];
    float bnx = TL2E * bhh[6 + jj];

    // input-projection rows for this lane's 3 gates (prescaled tables)
    const float* Wb = wih1t + branch * 108;
    const float* Bv = bih1t + branch * 18;
    int dgr = dir * 9 + jj, dgz = dgr + 3, dgn = dgr + 6;
    float Wr[6], Wz[6], Wn[6];
#pragma unroll
    for (int q = 0; q < 6; ++q) {
        Wr[q] = Wb[dgr * 6 + q];
        Wz[q] = Wb[dgz * 6 + q];
        Wn[q] = Wb[dgn * 6 + q];
    }
    float Br = Bv[dgr], Bz = Bv[dgz], Bn = Bv[dgn];

    const float4* o0 = (const float4*)out0 + (size_t)((branch * 2 + 0) * BB + b) * LL;
    const float4* o1 = (const float4*)out0 + (size_t)((branch * 2 + 1) * BB + b) * LL;

    int t0 = c * 32 - 64;
    float4 bf[8], bg[8];
#pragma unroll
    for (int s = 0; s < 8; ++s) {
        int tt = t0 + s; tt = tt < 0 ? 0 : tt;
        int l = dir ? (LL - 1 - tt) : tt;
        bf[s] = o0[l]; bg[s] = o1[l];
    }
    int pft = t0 + 8;

    char* ob = (char*)out1 + (size_t)chain * (LL * 16) + sub * 32;

    float h = 0.f;
    for (int g = 0; g < 12; ++g) {
#pragma unroll
        for (int s = 0; s < 8; ++s) {
            int t = t0 + g * 8 + s;
            float4 f4 = bf[s], q4 = bg[s];
            int tt = pft < 0 ? 0 : (pft > LL - 1 ? LL - 1 : pft);
            int lpf = dir ? (LL - 1 - tt) : tt;
            bf[s] = o0[lpf]; bg[s] = o1[lpf];
            ++pft;

            float gr = Br, gz = Bz, gn = Bn;
            gr = fmaf(f4.x, Wr[0], gr); gr = fmaf(f4.y, Wr[1], gr); gr = fmaf(f4.z, Wr[2], gr);
            gr = fmaf(q4.x, Wr[3], gr); gr = fmaf(q4.y, Wr[4], gr); gr = fmaf(q4.z, Wr[5], gr);
            gz = fmaf(f4.x, Wz[0], gz); gz = fmaf(f4.y, Wz[1], gz); gz = fmaf(f4.z, Wz[2], gz);
            gz = fmaf(q4.x, Wz[3], gz); gz = fmaf(q4.y, Wz[4], gz); gz = fmaf(q4.z, Wz[5], gz);
            gn = fmaf(f4.x, Wn[0], gn); gn = fmaf(f4.y, Wn[1], gn); gn = fmaf(f4.z, Wn[2], gn);
            gn = fmaf(q4.x, Wn[3], gn); gn = fmaf(q4.y, Wn[4], gn); gn = fmaf(q4.z, Wn[5], gn);

            float h0 = qb<0>(h), h1 = qb<1>(h), h2 = qb<2>(h);
            float hm1 = h - 1.f;
            float sr = fmaf(wr0, h0, gr) + fmaf(wr1, h1, wr2 * h2);
            float sz = fmaf(wz0, h0, gz) + fmaf(wz1, h1, wz2 * h2);
            float gn3 = fmaf(wn0, h0, fmaf(wn1, h1, fmaf(wn2, h2, bnx)));
            float r = rcp_(1.f + exp2_(sr));
            float z = rcp_(1.f + exp2_(sz));
            float y2 = fmaf(r, gn3, gn);
            float u = rcp_(1.f + exp2_(y2));
            float a = fmaf(2.f, u, hm1);
            float n = fmaf(-2.f, u, 1.f);
            float hn = fmaf(z, a, n);
            h = (t >= 0) ? hn : 0.f;
            lbuf[s * 81 + c * 5 + sub] = h;
        }
        __syncthreads();
        if (g >= 8) {
            int tbase = t0 + g * 8;
            int l0 = dir ? (LL - 1 - tbase - 7) : tbase;
#pragma unroll
            for (int i = 0; i < 2; ++i) {
                int lofs = sub * 2 + i;
                int s = dir ? (7 - lofs) : lofs;
                float4 vv;
                vv.x = lbuf[s * 81 + c * 5 + 0];
                vv.y = lbuf[s * 81 + c * 5 + 1];
                vv.z = lbuf[s * 81 + c * 5 + 2];
                vv.w = lbuf[s * 81 + c * 5 + 3];
                *(float4*)(ob + (size_t)l0 * 16 + i * 16) = vv;
            }
        }
        __syncthreads();
    }
}

// ---------------------------------------------------------------------------
// 6. Fused head: attention over wd_out + posfc/auxi + fc1/fc2 softmax.
// ---------------------------------------------------------------------------
__global__ void k_head(const float* __restrict__ out1,
                       const float* __restrict__ sw, const float* __restrict__ ap,
                       const float* __restrict__ pg, const float* __restrict__ pb,
                       const float* __restrict__ pw, const float* __restrict__ pbias,
                       const float* __restrict__ f1w, const float* __restrict__ f1b,
                       const float* __restrict__ fg, const float* __restrict__ fb,
                       const float* __restrict__ f2w, const float* __restrict__ f2b,
                       float* __restrict__ out)
{
    int b = blockIdx.x;
    int lane = threadIdx.x;
    __shared__ float ssw[36], sap[6], sph[6], scomb[9], sh[128], sl[6], se[6];
    const float BN = 0.9999950000374997f; // 1/sqrt(1+1e-5)

    if (lane < 36) ssw[lane] = sw[lane];
    if (lane < 6) {
        sap[lane] = ap[lane];
        const float* posf = out1 + (size_t)((2 * BB) + b) * LL * 4 + 511 * 4;
        const float* posb = out1 + (size_t)((3 * BB) + b) * LL * 4 + 511 * 4;
        float v = lane < 3 ? posf[lane] : posb[lane - 3];
        float x = v * BN * pg[lane] + pb[lane];
        sph[lane] = fmaxf(x, 0.f);
    }
    __syncthreads();

    const float* F = out1 + (size_t)b * LL * 4;
    const float* Bw = out1 + (size_t)(BB + b) * LL * 4;

    float att[8];
    float mx = -1e30f;
#pragma unroll
    for (int k = 0; k < 8; ++k) {
        int l = lane + 64 * k;
        float4 f4 = *(const float4*)(F + l * 4);
        float4 b4 = *(const float4*)(Bw + l * 4);
        float r0 = f4.x, r1 = f4.y, r2 = f4.z, r3 = b4.x, r4 = b4.y, r5 = b4.z;
        float a = 0.f;
#pragma unroll
        for (int j = 0; j < 6; ++j) {
            float s = r0 * ssw[0 * 6 + j] + r1 * ssw[1 * 6 + j] + r2 * ssw[2 * 6 + j] +
                      r3 * ssw[3 * 6 + j] + r4 * ssw[4 * 6 + j] + r5 * ssw[5 * 6 + j];
            a += sap[j] * tanh_(s);
        }
        att[k] = a;
        mx = fmaxf(mx, a);
    }
#pragma unroll
    for (int off = 32; off; off >>= 1) mx = fmaxf(mx, __shfl_xor(mx, off));
    float e[8];
    float sum = 0.f;
#pragma unroll
    for (int k = 0; k < 8; ++k) { e[k] = exp2_(L2E * (att[k] - mx)); sum += e[k]; }
#pragma unroll
    for (int off = 32; off; off >>= 1) sum += __shfl_xor(sum, off);

    float acc[6] = {0.f, 0.f, 0.f, 0.f, 0.f, 0.f};
#pragma unroll
    for (int k = 0; k < 8; ++k) {
        int l = lane + 64 * k;
        float4 f4 = *(const float4*)(F + l * 4);
        float4 b4 = *(const float4*)(Bw + l * 4);
        acc[0] += e[k] * f4.x; acc[1] += e[k] * f4.y; acc[2] += e[k] * f4.z;
        acc[3] += e[k] * b4.x; acc[4] += e[k] * b4.y; acc[5] += e[k] * b4.z;
    }
#pragma unroll
    for (int j = 0; j < 6; ++j) {
#pragma unroll
        for (int off = 32; off; off >>= 1) acc[j] += __shfl_xor(acc[j], off);
    }
    if (lane < 6) scomb[lane] = acc[lane] / sum;
    __syncthreads();

    if (lane == 0) {
        float a[3];
#pragma unroll
        for (int j = 0; j < 3; ++j) {
            float t = pbias[j];
#pragma unroll
            for (int i = 0; i < 6; ++i) t += sph[i] * pw[j * 6 + i];
            a[j] = t;
        }
        float m = fmaxf(a[0], fmaxf(a[1], a[2]));
        float e0 = exp2_(L2E * (a[0] - m)), e1 = exp2_(L2E * (a[1] - m)), e2 = exp2_(L2E * (a[2] - m));
        float s = e0 + e1 + e2;
        float x0 = e0 / s, x1 = e1 / s, x2 = e2 / s;
        scomb[6] = x0; scomb[7] = x1; scomb[8] = x2;
        out[BB * 6 + b * 3 + 0] = x0;
        out[BB * 6 + b * 3 + 1] = x1;
        out[BB * 6 + b * 3 + 2] = x2;
    }
    __syncthreads();
    for (int o = lane; o < 128; o += 64) {
        float t = f1b[o];
#pragma unroll
        for (int k = 0; k < 9; ++k) t += scomb[k] * f1w[o * 9 + k];
        float x = t * BN * fg[o] + fb[o];
        sh[o] = fmaxf(x, 0.f);
    }
    __syncthreads();
    if (lane < 6) {
        float t = f2b[lane];
        for (int k = 0; k < 128; ++k) t += sh[k] * f2w[lane * 128 + k];
        sl[lane] = t;
    }
    __syncthreads();
    if (lane < 6) {
        float m = sl[0];
#pragma unroll
        for (int j = 1; j < 6; ++j) m = fmaxf(m, sl[j]);
        se[lane] = exp2_(L2E * (sl[lane] - m));
    }
    __syncthreads();
    if (lane < 6) {
        float s = se[0] + se[1] + se[2] + se[3] + se[4] + se[5];
        out[b * 6 + lane] = se[lane] / s;
    }
}

// ---------------------------------------------------------------------------
extern "C" void kernel_launch(void* const* d_in, const int* in_sizes, int n_in,
                              void* d_out, int out_size, void* d_ws, size_t ws_size,
                              hipStream_t stream)
{
    const int* wd  = (const int*)d_in[0];
    const int* pos = (const int*)d_in[1];
    const float* wd_emb  = (const float*)d_in[2];
    const float* pos_emb = (const float*)d_in[3];
    const float* cw2 = (const float*)d_in[4];  const float* cb2 = (const float*)d_in[5];
    const float* cw3 = (const float*)d_in[6];  const float* cb3 = (const float*)d_in[7];
    const float* cw4 = (const float*)d_in[8];  const float* cb4 = (const float*)d_in[9];
    const float* wd_wih0 = (const float*)d_in[10]; const float* wd_whh0 = (const float*)d_in[11];
    const float* wd_bih0 = (const float*)d_in[12]; const float* wd_bhh0 = (const float*)d_in[13];
    const float* wd_wih1 = (const float*)d_in[14]; const float* wd_whh1 = (const float*)d_in[15];
    const float* wd_bih1 = (const float*)d_in[16]; const float* wd_bhh1 = (const float*)d_in[17];
    const float* pos_wih0 = (const float*)d_in[18]; const float* pos_whh0 = (const float*)d_in[19];
    const float* pos_bih0 = (const float*)d_in[20]; const float* pos_bhh0 = (const float*)d_in[21];
    const float* pos_wih1 = (const float*)d_in[22]; const float* pos_whh1 = (const float*)d_in[23];
    const float* pos_bih1 = (const float*)d_in[24]; const float* pos_bhh1 = (const float*)d_in[25];
    const float* squish_w   = (const float*)d_in[26];
    const float* atten_proj = (const float*)d_in[27];
    const float* posfc_gamma = (const float*)d_in[28]; const float* posfc_beta = (const float*)d_in[29];
    const float* posfc_w = (const float*)d_in[30]; const float* posfc_b = (const float*)d_in[31];
    const float* fc1_w = (const float*)d_in[32]; const float* fc1_b = (const float*)d_in[33];
    const float* fc_gamma = (const float*)d_in[34]; const float* fc_beta = (const float*)d_in[35];
    const float* fc2_w = (const float*)d_in[36]; const float* fc2_b = (const float*)d_in[37];

    float* ws = (float*)d_ws;
    size_t off = 0;
    float* P = ws + off;      off += (size_t)VV * 72 + 8;        // 1,710,512
    float* gx = ws + off;     off += (size_t)4 * BB * LL * 9;    // 9,437,184
    float* out0 = ws + off;   off += (size_t)4 * BB * LL * 4;    // 4,194,304
    float* out1 = ws + off;   off += (size_t)4 * BB * LL * 4;    // 4,194,304
    float* Etab = ws + off;   off += 7200;
    float* beff = ws + off;   off += 32;
    float* Gp = ws + off;     off += PP * 18 + 14;
    float* wih1t = ws + off;  off += 216;
    float* bih1t = ws + off;  off += 40;

    k_build_tables<<<(8496 + 255) / 256, 256, 0, stream>>>(
        wd_wih0, wd_bih0, wd_bhh0, cw2, cb2, cw3, cb3, cw4, cb4,
        pos_emb, pos_wih0, pos_bih0, pos_bhh0,
        wd_wih1, wd_bih1, wd_bhh1, pos_wih1, pos_bih1, pos_bhh1,
        Etab, beff, Gp, wih1t, bih1t);
    {
        int vb = (VV + 3) / 4;
        int threads = vb * 8;
        k_build_P<<<(threads + 255) / 256, 256, 0, stream>>>(wd_emb, Etab, P);
    }
    k_gather<<<(2 * BB * LL + 255) / 256, 256, 0, stream>>>(wd, pos, P, beff, Gp, gx);
    k_scan<<<2048, 64, 0, stream>>>(gx, out0, wd_whh0, wd_bhh0, pos_whh0, pos_bhh0);
    k_scan1<<<2048, 64, 0, stream>>>(out0, out1, wd_whh1, wd_bhh1, pos_whh1, pos_bhh1,
                                     wih1t, bih1t);
    k_head<<<BB, 64, 0, stream>>>(out1, squish_w, atten_proj, posfc_gamma, posfc_beta,
                                  posfc_w, posfc_b, fc1_w, fc1_b, fc_gamma, fc_beta,
                                  fc2_w, fc2_b, (float*)d_out);
}